// Round 4
// baseline (172.595 us; speedup 1.0000x reference)
//
#include <hip/hip_runtime.h>
#include <hip/hip_bf16.h>

#define BN 2
#define SDIM 2048
#define EDIM 1024
#define HN 16
#define DDIM 64

typedef __attribute__((ext_vector_type(8))) short bfrag;
typedef __attribute__((ext_vector_type(4))) float ffrag;

__device__ __forceinline__ ffrag mfma16(bfrag a, bfrag b, ffrag c) {
    return __builtin_amdgcn_mfma_f32_16x16x32_bf16(a, b, c, 0, 0, 0);
}

__device__ __forceinline__ ushort f2bf(float f) {
    union { float f; unsigned u; } un;
    un.f = f;
    unsigned u = un.u;
    u += 0x7fffu + ((u >> 16) & 1u);   // RNE
    return (ushort)(u >> 16);
}

__device__ __forceinline__ uint pkbf2(float a, float b) {
    __hip_bfloat162 h = __float22bfloat162_rn(make_float2(a, b));
    union { __hip_bfloat162 h; uint u; } cv;
    cv.h = h;
    return cv.u;
}

// async global->LDS: 16B/lane; LDS dest = wave-uniform base + lane*16
__device__ __forceinline__ void gld16(const void* g, void* l) {
    __builtin_amdgcn_global_load_lds((const __attribute__((address_space(1))) void*)g,
                                     (__attribute__((address_space(3))) void*)l,
                                     16, 0, 0);
}

// ---------------- fused fp32 -> bf16 conversion ----------------
__global__ __launch_bounds__(256) void to_bf16_3(const float* __restrict__ a, ushort* __restrict__ oa, int na,
                                                 const float* __restrict__ b, ushort* __restrict__ ob, int nb,
                                                 const float* __restrict__ c, ushort* __restrict__ oc, int nc) {
    int i = (blockIdx.x * 256 + threadIdx.x) * 4;
    const float* src;
    ushort* dst;
    if (i < na)                { src = a + i;            dst = oa + i; }
    else if (i < na + nb)      { src = b + (i - na);     dst = ob + (i - na); }
    else if (i < na + nb + nc) { src = c + (i - na - nb); dst = oc + (i - na - nb); }
    else return;
    float4 v = *(const float4*)src;
    uint2 u;
    u.x = pkbf2(v.x, v.y);
    u.y = pkbf2(v.z, v.w);
    *(uint2*)dst = u;
}

// ---------------- QKV GEMM: 256x192 tile, 4-phase/K-tile counted-vmcnt schedule ----------------
// 8 waves (2M x 4N), wave tile 128x48. LDS: 2 bufs x (A 256x64 + B 192x64) bf16 = 112 KiB.
// Staging rounds (1 gld16/thread each, 64 rows): A.r0..r3, B.r0..r2 (7/tile).
// Deadness-derived schedule (race-free, steady-state vmcnt(5)):
//   iter t, reading buf b=t&1:
//     ph0: issue t+1's A.r1 -> b^1 (idle buf)      ph1: issue t+1's A.r3 -> b^1
//     ph2: issue t+2's A.r0, A.r2, B.r0 -> b       (A.r0/A.r2 rows dead after ph1; B dead after ph0)
//     ph3: issue t+2's B.r1, B.r2 -> b
//     ph3 end: vmcnt(5) [t+1 landed, t+2's early-5 in flight]; raw s_barrier (no implicit drain).
// Epilogue additionally produces per-tile V column sums (T) via block-local LDS reduction:
// each (bh, s-tile, d) is covered by exactly one block (256 rows = 4 tiles of one b;
// 192 cols = 3 head-slices), so no global atomics are needed.
template <int UNUSED>
__global__ __launch_bounds__(512, 2) void gemm256_qkv(const ushort* __restrict__ A,
                                                      const ushort* __restrict__ Bt,
                                                      const float* __restrict__ bias,
                                                      ushort* __restrict__ Cout,
                                                      float* __restrict__ T,
                                                      int M, int N, int K) {
    constexpr int BM = 256, BNT = 192;
    constexpr int A_USH = BM * 64;           // 16384
    constexpr int B_USH = BNT * 64;          // 12288
    constexpr int BUF_USH = A_USH + B_USH;   // 28672
    __shared__ ushort lds[2 * BUF_USH];      // 112 KiB -> 1 block/CU
    __shared__ float Tred[4 * BNT];          // 3 KiB: [tile_local][col_local] V sums

    const int tid  = threadIdx.x;
    const int wave = tid >> 6;
    const int lane = tid & 63;
    const int ln16 = lane & 15;
    const int quad = lane >> 4;
    const int wm   = wave >> 2;              // 0..1
    const int wn   = wave & 3;               // 0..3
    const int bm   = blockIdx.x * BM;
    const int bn   = blockIdx.y * BNT;

    const int r0 = tid >> 3;                 // 0..63
    const int c0 = ((tid & 7) - r0) & 7;     // inverse rotate swizzle
    const ushort* Abase = A  + (size_t)(bm + r0) * K + c0 * 8;
    const ushort* Bbase = Bt + (size_t)(bn + r0) * K + c0 * 8;
    const int ldst0 = wave * 512;            // wave-uniform chunk base (ushorts) within round

    const int Ra = wm * 128 + ln16;
    const int Rb = wn * 48 + ln16;
    int aoff[2], boff[2];
#pragma unroll
    for (int kb = 0; kb < 2; ++kb) {
        aoff[kb] = Ra * 64 + ((kb * 4 + quad + Ra) & 7) * 8;
        boff[kb] = A_USH + Rb * 64 + ((kb * 4 + quad + Rb) & 7) * 8;
    }

    ffrag acc[8][3];
#pragma unroll
    for (int mi = 0; mi < 8; ++mi)
#pragma unroll
        for (int ni = 0; ni < 3; ++ni)
            acc[mi][ni] = (ffrag){0.f, 0.f, 0.f, 0.f};

    const int nt = K >> 6;                   // 16

    auto stA = [&](int buf, int t, int rnd) {
        gld16(Abase + (size_t)rnd * 64 * K + t * 64,
              &lds[buf * BUF_USH + rnd * 4096 + ldst0]);
    };
    auto stB = [&](int buf, int t, int rnd) {
        gld16(Bbase + (size_t)rnd * 64 * K + t * 64,
              &lds[buf * BUF_USH + A_USH + rnd * 4096 + ldst0]);
    };

    // prologue: tile0 full (7) -> buf0; tile1 early-5 -> buf1
    stA(0, 0, 0); stA(0, 0, 1); stA(0, 0, 2); stA(0, 0, 3);
    stB(0, 0, 0); stB(0, 0, 1); stB(0, 0, 2);
    stA(1, 1, 0); stA(1, 1, 2);
    stB(1, 1, 0); stB(1, 1, 1); stB(1, 1, 2);
    asm volatile("s_waitcnt vmcnt(5)" ::: "memory");
    __builtin_amdgcn_s_barrier();

    for (int t = 0; t < nt; ++t) {
        const int buf = t & 1;
        const ushort* Al = &lds[buf * BUF_USH];
        const bool h1 = (t + 1) < nt;
        const bool h2 = (t + 2) < nt;
        bfrag bfr[3][2];
#pragma unroll
        for (int p = 0; p < 4; ++p) {
            bfrag afr[2][2];
#pragma unroll
            for (int m2 = 0; m2 < 2; ++m2)
#pragma unroll
                for (int kb = 0; kb < 2; ++kb)
                    afr[m2][kb] = *(const bfrag*)(Al + aoff[kb] + (p * 2 + m2) * 1024);
            if (p == 0) {
#pragma unroll
                for (int ni = 0; ni < 3; ++ni)
#pragma unroll
                    for (int kb = 0; kb < 2; ++kb)
                        bfr[ni][kb] = *(const bfrag*)(Al + boff[kb] + ni * 1024);
            }
            if (p == 0 && h1) stA(buf ^ 1, t + 1, 1);
            if (p == 1 && h1) stA(buf ^ 1, t + 1, 3);
            if (p == 2 && h2) { stA(buf, t + 2, 0); stA(buf, t + 2, 2); stB(buf, t + 2, 0); }
            if (p == 3 && h2) { stB(buf, t + 2, 1); stB(buf, t + 2, 2); }

            __builtin_amdgcn_s_barrier();
            asm volatile("s_waitcnt lgkmcnt(0)" ::: "memory");
            __builtin_amdgcn_sched_barrier(0);
            __builtin_amdgcn_s_setprio(1);
#pragma unroll
            for (int m2 = 0; m2 < 2; ++m2)
#pragma unroll
                for (int ni = 0; ni < 3; ++ni)
#pragma unroll
                    for (int kb = 0; kb < 2; ++kb)
                        acc[p * 2 + m2][ni] = mfma16(afr[m2][kb], bfr[ni][kb], acc[p * 2 + m2][ni]);
            __builtin_amdgcn_s_setprio(0);
            if (p == 3) {
                if (h2)      { asm volatile("s_waitcnt vmcnt(5)" ::: "memory"); }
                else if (h1) { asm volatile("s_waitcnt vmcnt(0)" ::: "memory"); }
            }
            __builtin_amdgcn_s_barrier();
        }
    }

    // does this block produce any V columns? (block-uniform -> barriers below are legal)
    const bool hasV = (bn + BNT - 1) >= 2 * EDIM;
    if (hasV) {
        for (int idx = tid; idx < 4 * BNT; idx += 512) Tred[idx] = 0.f;
        __syncthreads();
    }

    // epilogue: qkv scatter (q scaled 1/8, V transposed to [b,h,d,s]) + V tile-sum reduction
#pragma unroll
    for (int mi = 0; mi < 8; ++mi) {
#pragma unroll
        for (int ni = 0; ni < 3; ++ni) {
            int col = bn + wn * 48 + ni * 16 + ln16;
            float bc = bias[col];
            int row0 = bm + wm * 128 + mi * 16 + quad * 4;
            int which = col >> 10;
            int rem = col & 1023;
            int h = rem >> 6;
            int d = rem & 63;
            int b = row0 >> 11;
            int s0 = row0 & 2047;
            if (which == 2) {
                float v0 = acc[mi][ni][0] + bc, v1 = acc[mi][ni][1] + bc;
                float v2 = acc[mi][ni][2] + bc, v3 = acc[mi][ni][3] + bc;
                uint2 pk;
                pk.x = pkbf2(v0, v1);
                pk.y = pkbf2(v2, v3);
                size_t dst = 2ull * (BN * HN * SDIM * DDIM) +
                             (((size_t)(b * HN + h)) * DDIM + d) * SDIM + s0;
                *(uint2*)(Cout + dst) = pk;
                // V tile-sum: this thread's 4 regs are 4 consecutive s in one 64-tile
                int tl = (wm * 128 + mi * 16 + quad * 4) >> 6;        // 0..3
                int cl = wn * 48 + ni * 16 + ln16;                     // 0..191
                atomicAdd(&Tred[tl * BNT + cl], v0 + v1 + v2 + v3);
            } else {
                float sc = (which == 0) ? 0.125f : 1.f;
#pragma unroll
                for (int reg = 0; reg < 4; ++reg) {
                    float v = (acc[mi][ni][reg] + bc) * sc;
                    size_t dst = (size_t)which * (BN * HN * SDIM * DDIM) +
                                 (((size_t)(b * HN + h)) * SDIM + s0 + reg) * DDIM + d;
                    Cout[dst] = f2bf(v);
                }
            }
        }
    }

    if (hasV) {
        __syncthreads();
        for (int idx = tid; idx < 4 * BNT; idx += 512) {
            int tl = idx / BNT, cl = idx % BNT;
            int col = bn + cl;
            if (col >= 2 * EDIM) {
                int rem = col - 2 * EDIM;
                int h = rem >> 6, d = rem & 63;
                int b = bm >> 11;
                int tile_g = ((bm & 2047) >> 6) + tl;                  // 0..31
                T[(((size_t)(b * HN + h)) * 32 + tile_g) * 64 + d] = Tred[idx];
            }
        }
    }
}

// ---------------- out-projection GEMM: 128x128 tile, 2-phase counted-vmcnt ----------------
// 8 waves (2M x 4N), wave tile 64x32, acc[4][2]. LDS: 2 bufs x (A 128x64 + B 128x64) = 64 KiB
// -> 2 blocks/CU (16 waves/CU). Per K-tile: 4 staging rounds (A.r0,A.r1,B.r0,B.r1).
// Schedule per iter t (reading buf t&1):
//   [12 ds_read_b128][lgkmcnt(0)][barrier1]            <- all waves' LDS reads drained
//   [stage t+2 -> buf (now dead)][MFMA x16 setprio]
//   [vmcnt(4): t+1 landed, t+2 in flight][barrier2]
__global__ __launch_bounds__(512, 4) void gemm128_op(const ushort* __restrict__ A,
                                                     const ushort* __restrict__ Bt,
                                                     const float* __restrict__ bias,
                                                     float* __restrict__ C,
                                                     int M, int N, int K) {
    constexpr int BM = 128, BNT = 128;
    constexpr int A_USH = BM * 64;           // 8192
    constexpr int B_USH = BNT * 64;          // 8192
    constexpr int BUF_USH = A_USH + B_USH;   // 16384
    __shared__ ushort lds[2 * BUF_USH];      // 64 KiB

    const int tid  = threadIdx.x;
    const int wave = tid >> 6;
    const int lane = tid & 63;
    const int ln16 = lane & 15;
    const int quad = lane >> 4;
    const int wm   = wave >> 2;              // 0..1
    const int wn   = wave & 3;               // 0..3
    const int bm   = blockIdx.x * BM;
    const int bn   = blockIdx.y * BNT;

    const int r0 = tid >> 3;                 // 0..63 (row within 64-row round)
    const int c0 = ((tid & 7) - r0) & 7;     // inverse rotate swizzle
    const ushort* Abase = A  + (size_t)(bm + r0) * K + c0 * 8;
    const ushort* Bbase = Bt + (size_t)(bn + r0) * K + c0 * 8;
    const int ldst0 = wave * 512;

    const int Ra = wm * 64 + ln16;
    const int Rb = wn * 32 + ln16;
    int aoff[2], boff[2];
#pragma unroll
    for (int kb = 0; kb < 2; ++kb) {
        aoff[kb] = Ra * 64 + ((kb * 4 + quad + Ra) & 7) * 8;
        boff[kb] = A_USH + Rb * 64 + ((kb * 4 + quad + Rb) & 7) * 8;
    }

    ffrag acc[4][2];
#pragma unroll
    for (int mi = 0; mi < 4; ++mi)
#pragma unroll
        for (int ni = 0; ni < 2; ++ni)
            acc[mi][ni] = (ffrag){0.f, 0.f, 0.f, 0.f};

    const int nt = K >> 6;                   // 16

    auto stA = [&](int buf, int t, int rnd) {
        gld16(Abase + (size_t)rnd * 64 * K + t * 64,
              &lds[buf * BUF_USH + rnd * 4096 + ldst0]);
    };
    auto stB = [&](int buf, int t, int rnd) {
        gld16(Bbase + (size_t)rnd * 64 * K + t * 64,
              &lds[buf * BUF_USH + A_USH + rnd * 4096 + ldst0]);
    };

    // prologue: tile0 -> buf0, tile1 -> buf1; wait tile0 (4 newest stay in flight)
    stA(0, 0, 0); stA(0, 0, 1); stB(0, 0, 0); stB(0, 0, 1);
    stA(1, 1, 0); stA(1, 1, 1); stB(1, 1, 0); stB(1, 1, 1);
    asm volatile("s_waitcnt vmcnt(4)" ::: "memory");
    __builtin_amdgcn_s_barrier();

    for (int t = 0; t < nt; ++t) {
        const int buf = t & 1;
        const ushort* Al = &lds[buf * BUF_USH];
        bfrag afr[4][2], bfr[2][2];
#pragma unroll
        for (int mi = 0; mi < 4; ++mi)
#pragma unroll
            for (int kb = 0; kb < 2; ++kb)
                afr[mi][kb] = *(const bfrag*)(Al + aoff[kb] + mi * 1024);
#pragma unroll
        for (int ni = 0; ni < 2; ++ni)
#pragma unroll
            for (int kb = 0; kb < 2; ++kb)
                bfr[ni][kb] = *(const bfrag*)(Al + boff[kb] + ni * 1024);
        asm volatile("s_waitcnt lgkmcnt(0)" ::: "memory");
        __builtin_amdgcn_sched_barrier(0);
        __builtin_amdgcn_s_barrier();        // barrier1: every wave's reads drained

        if (t + 2 < nt) {                    // stage t+2 into the now-dead current buf
            stA(buf, t + 2, 0); stA(buf, t + 2, 1);
            stB(buf, t + 2, 0); stB(buf, t + 2, 1);
        }

        __builtin_amdgcn_s_setprio(1);
#pragma unroll
        for (int mi = 0; mi < 4; ++mi)
#pragma unroll
            for (int ni = 0; ni < 2; ++ni)
#pragma unroll
                for (int kb = 0; kb < 2; ++kb)
                    acc[mi][ni] = mfma16(afr[mi][kb], bfr[ni][kb], acc[mi][ni]);
        __builtin_amdgcn_s_setprio(0);

        if (t + 2 < nt)      { asm volatile("s_waitcnt vmcnt(4)" ::: "memory"); }
        else if (t + 1 < nt) { asm volatile("s_waitcnt vmcnt(0)" ::: "memory"); }
        __builtin_amdgcn_s_barrier();        // barrier2: next tile ready
    }

    // epilogue: fp32 row-major + bias
#pragma unroll
    for (int mi = 0; mi < 4; ++mi) {
#pragma unroll
        for (int ni = 0; ni < 2; ++ni) {
            int col = bn + wn * 32 + ni * 16 + ln16;
            float bc = bias[col];
            int row0 = bm + wm * 64 + mi * 16 + quad * 4;
#pragma unroll
            for (int reg = 0; reg < 4; ++reg)
                C[(size_t)(row0 + reg) * N + col] = acc[mi][ni][reg] + bc;
        }
    }
}

// ---------------- flash attention with near-band + closed-form far field ----------------
__global__ __launch_bounds__(512, 4) void flash_attn(const ushort* __restrict__ Qb,
                                                     const ushort* __restrict__ Kb,
                                                     const ushort* __restrict__ Vtb,
                                                     const float* __restrict__ decay_ptr,
                                                     const float* __restrict__ T,
                                                     ushort* __restrict__ Ob) {
    __shared__ ushort KVs[2][2][4096];   // [buf][K / Vt][64 rows x 8 chunks, swizzled]
    __shared__ ushort Pb[128][72];       // Q staging, then P exchange (per-wave rows)
    __shared__ float  Fv[64];            // far-field V sum per d

    const int tid  = threadIdx.x;
    const int wave = tid >> 6;
    const int lane = tid & 63;
    const int ln16 = lane & 15;
    const int quad = lane >> 4;

    const int bh = blockIdx.y;
    const int q0 = blockIdx.x * 128;
    const size_t head_off = (size_t)bh * SDIM * DDIM;
    const float absa = fabsf(decay_ptr[0]);
    const float LOG2E = 1.442695041f;
    const float M0L2 = -17.3123404f;     // -12 * log2(e)
    const float E12 = 6.144212353e-6f;   // e^-12

    int Dstar = (absa > 1e-5f) ? (int)ceilf(16.0f / absa) : (4 * SDIM);
    int lo = q0 - 63 - Dstar; if (lo < 0) lo = 0;
    int hi = q0 + 127 + Dstar; if (hi > SDIM - 1) hi = SDIM - 1;
    const int tlo = lo >> 6;
    const int thi = hi >> 6;
    const int ntiles = thi - tlo + 1;

    if (tid < 64) {
        const float* Tp = T + (size_t)bh * 32 * 64;
        float s = 0.f;
        for (int k = 0; k < tlo; ++k)      s += Tp[k * 64 + tid];
        for (int k = thi + 1; k < 32; ++k) s += Tp[k * 64 + tid];
        Fv[tid] = s;
    }

    auto stageKV = [&](int t0, int buf) {
        int g0 = wave * 64;
        int g  = g0 + lane;
        int r  = g >> 3;
        int c  = (g - r) & 7;            // inverse swizzle
        gld16(Kb  + head_off + (size_t)(t0 + r) * DDIM + c * 8,
              (ushort*)&KVs[buf][0][0] + g0 * 8);
        gld16(Vtb + head_off + (size_t)r * SDIM + t0 + c * 8,
              (ushort*)&KVs[buf][1][0] + g0 * 8);
    };

#pragma unroll
    for (int p = 0; p < 2; ++p) {
        int idx = p * 512 + tid;
        int r = idx >> 3, c = (idx & 7) * 8;
        *(uint4*)&Pb[r][c] = *(const uint4*)(Qb + head_off + (size_t)(q0 + r) * DDIM + c);
    }
    stageKV(tlo * 64, 0);
    __syncthreads();

    bfrag aq[2];
#pragma unroll
    for (int kb = 0; kb < 2; ++kb)
        aq[kb] = *(const bfrag*)&Pb[wave * 16 + ln16][kb * 32 + quad * 8];

    bfrag ones;
#pragma unroll
    for (int i = 0; i < 8; ++i) ones[i] = (short)0x3F80;   // bf16 1.0

    float EcB[4], FcB[4], Epw[4], Fpw[4];
#pragma unroll
    for (int reg = 0; reg < 4; ++reg) {
        int cr = quad * 4 + reg;
        EcB[reg] = __expf(-absa * (float)(15 - cr));
        FcB[reg] = __expf(-absa * (float)cr);
    }
#pragma unroll
    for (int ni = 0; ni < 4; ++ni) {
        Epw[ni] = __expf(-absa * (float)(16 * (3 - ni)));
        Fpw[ni] = __expf(-absa * (float)(16 * ni));
    }
    const float Er = __expf(-absa * (float)ln16);
    const float Fr = __expf(-absa * (float)(15 - ln16));

    ffrag lacc = (ffrag){0.f, 0.f, 0.f, 0.f};
    ffrag o[4];
#pragma unroll
    for (int ni = 0; ni < 4; ++ni) o[ni] = (ffrag){0.f, 0.f, 0.f, 0.f};

    const int m = wave * 16 + ln16;

    for (int it = 0; it < ntiles; ++it) {
        const int t0 = (tlo + it) * 64;
        const int buf = it & 1;
        if (it + 1 < ntiles) stageKV(t0 + 64, buf ^ 1);   // async prefetch

        const ushort* Kt = &KVs[buf][0][0];
        const ushort* Vt = &KVs[buf][1][0];

        ffrag sc[4];
#pragma unroll
        for (int ni = 0; ni < 4; ++ni) {
            ffrag a = (ffrag){0.f, 0.f, 0.f, 0.f};
            const int rk = ni * 16 + ln16;
#pragma unroll
            for (int kb = 0; kb < 2; ++kb) {
                bfrag kf = *(const bfrag*)&Kt[rk * 64 + ((kb * 4 + quad + rk) & 7) * 8];
                a = mfma16(kf, aq[kb], a);
            }
            sc[ni] = a;
        }

        const int ds = q0 + wave * 16 - t0;
        float hh = 0.f;
        if (ds >= 64)       hh = __expf(-absa * (float)(ds - 63)) * Er * LOG2E;
        else if (ds <= -16) hh = __expf(-absa * (float)(-ds - 15)) * Fr * LOG2E;

#pragma unroll
        for (int ni = 0; ni < 4; ++ni) {
            float f0, f1, f2, f3;
            if (ds >= 64) {
                float hn = hh * Epw[ni];
                f0 = hn * EcB[0]; f1 = hn * EcB[1]; f2 = hn * EcB[2]; f3 = hn * EcB[3];
            } else if (ds <= -16) {
                float hn = hh * Fpw[ni];
                f0 = hn * FcB[0]; f1 = hn * FcB[1]; f2 = hn * FcB[2]; f3 = hn * FcB[3];
            } else {
                int c0 = ni * 16 + quad * 4;
                f0 = __expf(-absa * fabsf((float)(ds + ln16 - c0)))     * LOG2E;
                f1 = __expf(-absa * fabsf((float)(ds + ln16 - c0 - 1))) * LOG2E;
                f2 = __expf(-absa * fabsf((float)(ds + ln16 - c0 - 2))) * LOG2E;
                f3 = __expf(-absa * fabsf((float)(ds + ln16 - c0 - 3))) * LOG2E;
            }
            float p0 = exp2f(fmaf(sc[ni][0], f0, M0L2));
            float p1 = exp2f(fmaf(sc[ni][1], f1, M0L2));
            float p2 = exp2f(fmaf(sc[ni][2], f2, M0L2));
            float p3 = exp2f(fmaf(sc[ni][3], f3, M0L2));
            uint2 pk;
            pk.x = pkbf2(p0, p1);
            pk.y = pkbf2(p2, p3);
            *(uint2*)&Pb[m][ni * 16 + quad * 4] = pk;   // own-wave rows: no barrier
        }

        bfrag ap[2];
#pragma unroll
        for (int kb = 0; kb < 2; ++kb)
            ap[kb] = *(const bfrag*)&Pb[m][kb * 32 + quad * 8];

#pragma unroll
        for (int kb = 0; kb < 2; ++kb)
            lacc = mfma16(ones, ap[kb], lacc);
#pragma unroll
        for (int ni = 0; ni < 4; ++ni) {
            const int rv = ni * 16 + ln16;
#pragma unroll
            for (int kb = 0; kb < 2; ++kb) {
                bfrag vf = *(const bfrag*)&Vt[rv * 64 + ((kb * 4 + quad + rv) & 7) * 8];
                o[ni] = mfma16(vf, ap[kb], o[ni]);
            }
        }
        __syncthreads();
    }

    const float farl = E12 * (float)(SDIM - 64 * ntiles);
    const float inv = 1.f / (lacc[0] + farl);
    const int b = bh / HN, h = bh % HN;
    const int s = q0 + m;
    ushort* dst = Ob + ((size_t)(b * SDIM + s)) * EDIM + h * DDIM + quad * 4;
#pragma unroll
    for (int ni = 0; ni < 4; ++ni) {
        int d0 = ni * 16 + quad * 4;
        float v0 = (o[ni][0] + E12 * Fv[d0 + 0]) * inv;
        float v1 = (o[ni][1] + E12 * Fv[d0 + 1]) * inv;
        float v2 = (o[ni][2] + E12 * Fv[d0 + 2]) * inv;
        float v3 = (o[ni][3] + E12 * Fv[d0 + 3]) * inv;
        uint2 pk;
        pk.x = pkbf2(v0, v1);
        pk.y = pkbf2(v2, v3);
        *(uint2*)(dst + ni * 16) = pk;
    }
}

extern "C" void kernel_launch(void* const* d_in, const int* in_sizes, int n_in,
                              void* d_out, int out_size, void* d_ws, size_t ws_size,
                              hipStream_t stream) {
    const float* x      = (const float*)d_in[0];
    const float* Wqkv_w = (const float*)d_in[1];
    const float* Wqkv_b = (const float*)d_in[2];
    const float* out_w  = (const float*)d_in[3];
    const float* out_b  = (const float*)d_in[4];
    const float* dd     = (const float*)d_in[5];

    char* ws = (char*)d_ws;
    const size_t MB = 1024 * 1024;
    ushort* xb    = (ushort*)(ws + 0 * MB);
    ushort* wqkvb = (ushort*)(ws + 8 * MB);
    ushort* owb   = (ushort*)(ws + 14 * MB);
    ushort* qkvb  = (ushort*)(ws + 16 * MB);   // q,k:[b,h,s,d] v:[b,h,d,s]
    ushort* ob    = (ushort*)(ws + 40 * MB);
    float*  Tp    = (float*)(ws + 48 * MB);    // 32*32*64*4 = 256 KB (own slab: written
                                               // by gemm256 epilogue while xb still live)

    const int n_x = BN * SDIM * EDIM;
    const int n_w = 3 * EDIM * EDIM;
    const int n_o = EDIM * EDIM;
    const int HSD = BN * HN * SDIM * DDIM;

    to_bf16_3<<<(n_x + n_w + n_o) / 1024, 256, 0, stream>>>(
        x, xb, n_x, Wqkv_w, wqkvb, n_w, out_w, owb, n_o);

    gemm256_qkv<0><<<dim3(16, 16), 512, 0, stream>>>(xb, wqkvb, Wqkv_b, qkvb, Tp,
                                                     BN * SDIM, 3 * EDIM, EDIM);

    flash_attn<<<dim3(SDIM / 128, BN * HN), 512, 0, stream>>>(
        qkvb, qkvb + HSD, qkvb + 2 * HSD, dd, Tp, ob);

    gemm128_op<<<dim3(32, 8), 512, 0, stream>>>(ob, owb, out_b, (float*)d_out,
                                                BN * SDIM, EDIM, EDIM);
}

// Round 6
// 164.879 us; speedup vs baseline: 1.0468x; 1.0468x over previous
//
#include <hip/hip_runtime.h>
#include <hip/hip_bf16.h>

#define BN 2
#define SDIM 2048
#define EDIM 1024
#define HN 16
#define DDIM 64

typedef __attribute__((ext_vector_type(8))) short bfrag;
typedef __attribute__((ext_vector_type(4))) float ffrag;

__device__ __forceinline__ ffrag mfma16(bfrag a, bfrag b, ffrag c) {
    return __builtin_amdgcn_mfma_f32_16x16x32_bf16(a, b, c, 0, 0, 0);
}

__device__ __forceinline__ ushort f2bf(float f) {
    union { float f; unsigned u; } un;
    un.f = f;
    unsigned u = un.u;
    u += 0x7fffu + ((u >> 16) & 1u);   // RNE
    return (ushort)(u >> 16);
}

__device__ __forceinline__ uint pkbf2(float a, float b) {
    __hip_bfloat162 h = __float22bfloat162_rn(make_float2(a, b));
    union { __hip_bfloat162 h; uint u; } cv;
    cv.h = h;
    return cv.u;
}

// async global->LDS: 16B/lane; LDS dest = wave-uniform base + lane*16
__device__ __forceinline__ void gld16(const void* g, void* l) {
    __builtin_amdgcn_global_load_lds((const __attribute__((address_space(1))) void*)g,
                                     (__attribute__((address_space(3))) void*)l,
                                     16, 0, 0);
}

// ---------------- fused fp32 -> bf16 conversion ----------------
__global__ __launch_bounds__(256) void to_bf16_3(const float* __restrict__ a, ushort* __restrict__ oa, int na,
                                                 const float* __restrict__ b, ushort* __restrict__ ob, int nb,
                                                 const float* __restrict__ c, ushort* __restrict__ oc, int nc) {
    int i = (blockIdx.x * 256 + threadIdx.x) * 4;
    const float* src;
    ushort* dst;
    if (i < na)                { src = a + i;            dst = oa + i; }
    else if (i < na + nb)      { src = b + (i - na);     dst = ob + (i - na); }
    else if (i < na + nb + nc) { src = c + (i - na - nb); dst = oc + (i - na - nb); }
    else return;
    float4 v = *(const float4*)src;
    uint2 u;
    u.x = pkbf2(v.x, v.y);
    u.y = pkbf2(v.z, v.w);
    *(uint2*)dst = u;
}

// ---------------- QKV GEMM: 256x192 tile, 4-phase/K-tile counted-vmcnt schedule ----------------
// 8 waves (2M x 4N), wave tile 128x48. LDS: 2 bufs x (A 256x64 + B 192x64) bf16 = 112 KiB.
// Staging rounds (1 gld16/thread each, 64 rows): A.r0..r3, B.r0..r2 (7/tile).
// Deadness-derived schedule (race-free):
//   iter t, reading buf b=t&1:
//     ph0: issue t+1's A.r1 -> b^1 (idle buf)      ph1: issue t+1's A.r3 -> b^1
//     ph2: issue t+2's A.r0, A.r2, B.r0 -> b       (A.r0/A.r2 rows dead after ph1; B dead after ph0)
//     ph3: issue t+2's B.r1, B.r2 -> b
// Wait discipline (per-wave queue audit, steady state):
//   p1-end vmcnt(7): pool=[ (t).A1,(t).A3, (t+1).early5, (t+1).A1,(t+1).A3 ]=9
//                    -> completes (t).A1,A3, needed by this iter's p2/p3 ds_reads.
//   p3-end vmcnt(7): pool=12 -> completes (t+1).{A0,A2,B0,B1,B2}, needed at t+1's p0.
//   Every load gets >=6 phases of issue-to-wait cover. Raw s_barrier (no implicit drain).
// XCD swizzle: linear id -> per-XCD 4x8 tile cluster (4 A-panels + 8 B-panels L2-resident).
template <int UNUSED>
__global__ __launch_bounds__(512, 2) void gemm256_qkv(const ushort* __restrict__ A,
                                                      const ushort* __restrict__ Bt,
                                                      const float* __restrict__ bias,
                                                      ushort* __restrict__ Cout,
                                                      int M, int N, int K) {
    constexpr int BM = 256, BNT = 192;
    constexpr int A_USH = BM * 64;           // 16384
    constexpr int B_USH = BNT * 64;          // 12288
    constexpr int BUF_USH = A_USH + B_USH;   // 28672
    __shared__ ushort lds[2 * BUF_USH];      // 112 KiB -> 1 block/CU

    const int tid  = threadIdx.x;
    const int wave = tid >> 6;
    const int lane = tid & 63;
    const int ln16 = lane & 15;
    const int quad = lane >> 4;
    const int wm   = wave >> 2;              // 0..1
    const int wn   = wave & 3;               // 0..3

    // XCD-aware bijective swizzle (grid fixed at 16x16; hw round-robin = lid%8)
    const int lid  = blockIdx.y * 16 + blockIdx.x;
    const int xcd  = lid & 7;
    const int rank = lid >> 3;               // 0..31
    const int tx   = (xcd & 3) * 4 + (rank & 3);    // 0..15 : 4 A-panels/XCD
    const int ty   = (xcd >> 2) * 8 + (rank >> 2);  // 0..15 : 8 B-panels/XCD
    const int bm   = tx * BM;
    const int bn   = ty * BNT;

    const int r0 = tid >> 3;                 // 0..63
    const int c0 = ((tid & 7) - r0) & 7;     // inverse rotate swizzle
    const ushort* Abase = A  + (size_t)(bm + r0) * K + c0 * 8;
    const ushort* Bbase = Bt + (size_t)(bn + r0) * K + c0 * 8;
    const int ldst0 = wave * 512;            // wave-uniform chunk base (ushorts) within round

    const int Ra = wm * 128 + ln16;
    const int Rb = wn * 48 + ln16;
    int aoff[2], boff[2];
#pragma unroll
    for (int kb = 0; kb < 2; ++kb) {
        aoff[kb] = Ra * 64 + ((kb * 4 + quad + Ra) & 7) * 8;
        boff[kb] = A_USH + Rb * 64 + ((kb * 4 + quad + Rb) & 7) * 8;
    }

    ffrag acc[8][3];
#pragma unroll
    for (int mi = 0; mi < 8; ++mi)
#pragma unroll
        for (int ni = 0; ni < 3; ++ni)
            acc[mi][ni] = (ffrag){0.f, 0.f, 0.f, 0.f};

    const int nt = K >> 6;                   // 16

    auto stA = [&](int buf, int t, int rnd) {
        gld16(Abase + (size_t)rnd * 64 * K + t * 64,
              &lds[buf * BUF_USH + rnd * 4096 + ldst0]);
    };
    auto stB = [&](int buf, int t, int rnd) {
        gld16(Bbase + (size_t)rnd * 64 * K + t * 64,
              &lds[buf * BUF_USH + A_USH + rnd * 4096 + ldst0]);
    };

    // prologue: tile0 full (7) -> buf0; tile1 early-5 -> buf1
    stA(0, 0, 0); stA(0, 0, 1); stA(0, 0, 2); stA(0, 0, 3);
    stB(0, 0, 0); stB(0, 0, 1); stB(0, 0, 2);
    stA(1, 1, 0); stA(1, 1, 2);
    stB(1, 1, 0); stB(1, 1, 1); stB(1, 1, 2);
    asm volatile("s_waitcnt vmcnt(5)" ::: "memory");
    __builtin_amdgcn_s_barrier();

    for (int t = 0; t < nt; ++t) {
        const int buf = t & 1;
        const ushort* Al = &lds[buf * BUF_USH];
        const bool h1 = (t + 1) < nt;
        const bool h2 = (t + 2) < nt;
        bfrag bfr[3][2];
#pragma unroll
        for (int p = 0; p < 4; ++p) {
            bfrag afr[2][2];
#pragma unroll
            for (int m2 = 0; m2 < 2; ++m2)
#pragma unroll
                for (int kb = 0; kb < 2; ++kb)
                    afr[m2][kb] = *(const bfrag*)(Al + aoff[kb] + (p * 2 + m2) * 1024);
            if (p == 0) {
#pragma unroll
                for (int ni = 0; ni < 3; ++ni)
#pragma unroll
                    for (int kb = 0; kb < 2; ++kb)
                        bfr[ni][kb] = *(const bfrag*)(Al + boff[kb] + ni * 1024);
            }
            if (p == 0 && h1) stA(buf ^ 1, t + 1, 1);
            if (p == 1 && h1) stA(buf ^ 1, t + 1, 3);
            if (p == 2 && h2) { stA(buf, t + 2, 0); stA(buf, t + 2, 2); stB(buf, t + 2, 0); }
            if (p == 3 && h2) { stB(buf, t + 2, 1); stB(buf, t + 2, 2); }

            __builtin_amdgcn_s_barrier();
            asm volatile("s_waitcnt lgkmcnt(0)" ::: "memory");
            __builtin_amdgcn_sched_barrier(0);
            __builtin_amdgcn_s_setprio(1);
#pragma unroll
            for (int m2 = 0; m2 < 2; ++m2)
#pragma unroll
                for (int ni = 0; ni < 3; ++ni)
#pragma unroll
                    for (int kb = 0; kb < 2; ++kb)
                        acc[p * 2 + m2][ni] = mfma16(afr[m2][kb], bfr[ni][kb], acc[p * 2 + m2][ni]);
            __builtin_amdgcn_s_setprio(0);
            if (p == 1) {
                if (h2)      { asm volatile("s_waitcnt vmcnt(7)" ::: "memory"); }
                else         { asm volatile("s_waitcnt vmcnt(0)" ::: "memory"); }
            }
            if (p == 3) {
                if (h2)      { asm volatile("s_waitcnt vmcnt(7)" ::: "memory"); }
                else if (h1) { asm volatile("s_waitcnt vmcnt(2)" ::: "memory"); }
            }
            __builtin_amdgcn_s_barrier();
        }
    }

    // epilogue: qkv scatter (q scaled 1/8, V transposed to [b,h,d,s])
#pragma unroll
    for (int mi = 0; mi < 8; ++mi) {
#pragma unroll
        for (int ni = 0; ni < 3; ++ni) {
            int col = bn + wn * 48 + ni * 16 + ln16;
            float bc = bias[col];
            int row0 = bm + wm * 128 + mi * 16 + quad * 4;
            int which = col >> 10;
            int rem = col & 1023;
            int h = rem >> 6;
            int d = rem & 63;
            int b = row0 >> 11;
            int s0 = row0 & 2047;
            if (which == 2) {
                float v0 = acc[mi][ni][0] + bc, v1 = acc[mi][ni][1] + bc;
                float v2 = acc[mi][ni][2] + bc, v3 = acc[mi][ni][3] + bc;
                uint2 pk;
                pk.x = pkbf2(v0, v1);
                pk.y = pkbf2(v2, v3);
                size_t dst = 2ull * (BN * HN * SDIM * DDIM) +
                             (((size_t)(b * HN + h)) * DDIM + d) * SDIM + s0;
                *(uint2*)(Cout + dst) = pk;
            } else {
                float sc = (which == 0) ? 0.125f : 1.f;
#pragma unroll
                for (int reg = 0; reg < 4; ++reg) {
                    float v = (acc[mi][ni][reg] + bc) * sc;
                    size_t dst = (size_t)which * (BN * HN * SDIM * DDIM) +
                                 (((size_t)(b * HN + h)) * SDIM + s0 + reg) * DDIM + d;
                    Cout[dst] = f2bf(v);
                }
            }
        }
    }
}

// ---------------- out-projection GEMM: 128x128 tile, 2-phase counted-vmcnt ----------------
// 8 waves (2M x 4N), wave tile 64x32, acc[4][2]. LDS: 2 bufs x (A 128x64 + B 128x64) = 64 KiB
// -> 2 blocks/CU (16 waves/CU). Per K-tile: 4 staging rounds (A.r0,A.r1,B.r0,B.r1).
// Schedule per iter t (reading buf t&1):
//   [12 ds_read_b128][lgkmcnt(0)][barrier1]            <- all waves' LDS reads drained
//   [stage t+2 -> buf (now dead)][MFMA x16 setprio]
//   [vmcnt(4): t+1 landed, t+2 in flight][barrier2]
__global__ __launch_bounds__(512, 4) void gemm128_op(const ushort* __restrict__ A,
                                                     const ushort* __restrict__ Bt,
                                                     const float* __restrict__ bias,
                                                     float* __restrict__ C,
                                                     int M, int N, int K) {
    constexpr int BM = 128, BNT = 128;
    constexpr int A_USH = BM * 64;           // 8192
    constexpr int B_USH = BNT * 64;          // 8192
    constexpr int BUF_USH = A_USH + B_USH;   // 16384
    __shared__ ushort lds[2 * BUF_USH];      // 64 KiB

    const int tid  = threadIdx.x;
    const int wave = tid >> 6;
    const int lane = tid & 63;
    const int ln16 = lane & 15;
    const int quad = lane >> 4;
    const int wm   = wave >> 2;              // 0..1
    const int wn   = wave & 3;               // 0..3
    const int bm   = blockIdx.x * BM;
    const int bn   = blockIdx.y * BNT;

    const int r0 = tid >> 3;                 // 0..63 (row within 64-row round)
    const int c0 = ((tid & 7) - r0) & 7;     // inverse rotate swizzle
    const ushort* Abase = A  + (size_t)(bm + r0) * K + c0 * 8;
    const ushort* Bbase = Bt + (size_t)(bn + r0) * K + c0 * 8;
    const int ldst0 = wave * 512;

    const int Ra = wm * 64 + ln16;
    const int Rb = wn * 32 + ln16;
    int aoff[2], boff[2];
#pragma unroll
    for (int kb = 0; kb < 2; ++kb) {
        aoff[kb] = Ra * 64 + ((kb * 4 + quad + Ra) & 7) * 8;
        boff[kb] = A_USH + Rb * 64 + ((kb * 4 + quad + Rb) & 7) * 8;
    }

    ffrag acc[4][2];
#pragma unroll
    for (int mi = 0; mi < 4; ++mi)
#pragma unroll
        for (int ni = 0; ni < 2; ++ni)
            acc[mi][ni] = (ffrag){0.f, 0.f, 0.f, 0.f};

    const int nt = K >> 6;                   // 16

    auto stA = [&](int buf, int t, int rnd) {
        gld16(Abase + (size_t)rnd * 64 * K + t * 64,
              &lds[buf * BUF_USH + rnd * 4096 + ldst0]);
    };
    auto stB = [&](int buf, int t, int rnd) {
        gld16(Bbase + (size_t)rnd * 64 * K + t * 64,
              &lds[buf * BUF_USH + A_USH + rnd * 4096 + ldst0]);
    };

    // prologue: tile0 -> buf0, tile1 -> buf1; wait tile0 (4 newest stay in flight)
    stA(0, 0, 0); stA(0, 0, 1); stB(0, 0, 0); stB(0, 0, 1);
    stA(1, 1, 0); stA(1, 1, 1); stB(1, 1, 0); stB(1, 1, 1);
    asm volatile("s_waitcnt vmcnt(4)" ::: "memory");
    __builtin_amdgcn_s_barrier();

    for (int t = 0; t < nt; ++t) {
        const int buf = t & 1;
        const ushort* Al = &lds[buf * BUF_USH];
        bfrag afr[4][2], bfr[2][2];
#pragma unroll
        for (int mi = 0; mi < 4; ++mi)
#pragma unroll
            for (int kb = 0; kb < 2; ++kb)
                afr[mi][kb] = *(const bfrag*)(Al + aoff[kb] + mi * 1024);
#pragma unroll
        for (int ni = 0; ni < 2; ++ni)
#pragma unroll
            for (int kb = 0; kb < 2; ++kb)
                bfr[ni][kb] = *(const bfrag*)(Al + boff[kb] + ni * 1024);
        asm volatile("s_waitcnt lgkmcnt(0)" ::: "memory");
        __builtin_amdgcn_sched_barrier(0);
        __builtin_amdgcn_s_barrier();        // barrier1: every wave's reads drained

        if (t + 2 < nt) {                    // stage t+2 into the now-dead current buf
            stA(buf, t + 2, 0); stA(buf, t + 2, 1);
            stB(buf, t + 2, 0); stB(buf, t + 2, 1);
        }

        __builtin_amdgcn_s_setprio(1);
#pragma unroll
        for (int mi = 0; mi < 4; ++mi)
#pragma unroll
            for (int ni = 0; ni < 2; ++ni)
#pragma unroll
                for (int kb = 0; kb < 2; ++kb)
                    acc[mi][ni] = mfma16(afr[mi][kb], bfr[ni][kb], acc[mi][ni]);
        __builtin_amdgcn_s_setprio(0);

        if (t + 2 < nt)      { asm volatile("s_waitcnt vmcnt(4)" ::: "memory"); }
        else if (t + 1 < nt) { asm volatile("s_waitcnt vmcnt(0)" ::: "memory"); }
        __builtin_amdgcn_s_barrier();        // barrier2: next tile ready
    }

    // epilogue: fp32 row-major + bias
#pragma unroll
    for (int mi = 0; mi < 4; ++mi) {
#pragma unroll
        for (int ni = 0; ni < 2; ++ni) {
            int col = bn + wn * 32 + ni * 16 + ln16;
            float bc = bias[col];
            int row0 = bm + wm * 64 + mi * 16 + quad * 4;
#pragma unroll
            for (int reg = 0; reg < 4; ++reg)
                C[(size_t)(row0 + reg) * N + col] = acc[mi][ni][reg] + bc;
        }
    }
}

// ---------------- per-head per-tile V sums (parallel) ----------------
__global__ __launch_bounds__(256) void vsum_tiles(const ushort* __restrict__ Vtb,
                                                  float* __restrict__ T) {
    const int bh   = blockIdx.x;
    const int tile = blockIdx.y * 4 + (threadIdx.x >> 6);
    const int d    = threadIdx.x & 63;
    const ushort* row = Vtb + ((size_t)bh * DDIM + d) * SDIM + tile * 64;
    float s = 0.f;
#pragma unroll
    for (int j = 0; j < 64; j += 8) {
        uint4 v = *(const uint4*)(row + j);
        ushort tmp[8];
        *(uint4*)tmp = v;
#pragma unroll
        for (int e = 0; e < 8; ++e) {
            union { float f; uint u; } c;
            c.u = ((uint)tmp[e]) << 16;
            s += c.f;
        }
    }
    T[((size_t)bh * 32 + tile) * 64 + d] = s;
}

// ---------------- flash attention with near-band + closed-form far field ----------------
__global__ __launch_bounds__(512, 4) void flash_attn(const ushort* __restrict__ Qb,
                                                     const ushort* __restrict__ Kb,
                                                     const ushort* __restrict__ Vtb,
                                                     const float* __restrict__ decay_ptr,
                                                     const float* __restrict__ T,
                                                     ushort* __restrict__ Ob) {
    __shared__ ushort KVs[2][2][4096];   // [buf][K / Vt][64 rows x 8 chunks, swizzled]
    __shared__ ushort Pb[128][72];       // Q staging, then P exchange (per-wave rows)
    __shared__ float  Fv[64];            // far-field V sum per d

    const int tid  = threadIdx.x;
    const int wave = tid >> 6;
    const int lane = tid & 63;
    const int ln16 = lane & 15;
    const int quad = lane >> 4;

    const int bh = blockIdx.y;
    const int q0 = blockIdx.x * 128;
    const size_t head_off = (size_t)bh * SDIM * DDIM;
    const float absa = fabsf(decay_ptr[0]);
    const float LOG2E = 1.442695041f;
    const float M0L2 = -17.3123404f;     // -12 * log2(e)
    const float E12 = 6.144212353e-6f;   // e^-12

    int Dstar = (absa > 1e-5f) ? (int)ceilf(16.0f / absa) : (4 * SDIM);
    int lo = q0 - 63 - Dstar; if (lo < 0) lo = 0;
    int hi = q0 + 127 + Dstar; if (hi > SDIM - 1) hi = SDIM - 1;
    const int tlo = lo >> 6;
    const int thi = hi >> 6;
    const int ntiles = thi - tlo + 1;

    if (tid < 64) {
        const float* Tp = T + (size_t)bh * 32 * 64;
        float s = 0.f;
        for (int k = 0; k < tlo; ++k)      s += Tp[k * 64 + tid];
        for (int k = thi + 1; k < 32; ++k) s += Tp[k * 64 + tid];
        Fv[tid] = s;
    }

    auto stageKV = [&](int t0, int buf) {
        int g0 = wave * 64;
        int g  = g0 + lane;
        int r  = g >> 3;
        int c  = (g - r) & 7;            // inverse swizzle
        gld16(Kb  + head_off + (size_t)(t0 + r) * DDIM + c * 8,
              (ushort*)&KVs[buf][0][0] + g0 * 8);
        gld16(Vtb + head_off + (size_t)r * SDIM + t0 + c * 8,
              (ushort*)&KVs[buf][1][0] + g0 * 8);
    };

#pragma unroll
    for (int p = 0; p < 2; ++p) {
        int idx = p * 512 + tid;
        int r = idx >> 3, c = (idx & 7) * 8;
        *(uint4*)&Pb[r][c] = *(const uint4*)(Qb + head_off + (size_t)(q0 + r) * DDIM + c);
    }
    stageKV(tlo * 64, 0);
    __syncthreads();

    bfrag aq[2];
#pragma unroll
    for (int kb = 0; kb < 2; ++kb)
        aq[kb] = *(const bfrag*)&Pb[wave * 16 + ln16][kb * 32 + quad * 8];

    bfrag ones;
#pragma unroll
    for (int i = 0; i < 8; ++i) ones[i] = (short)0x3F80;   // bf16 1.0

    float EcB[4], FcB[4], Epw[4], Fpw[4];
#pragma unroll
    for (int reg = 0; reg < 4; ++reg) {
        int cr = quad * 4 + reg;
        EcB[reg] = __expf(-absa * (float)(15 - cr));
        FcB[reg] = __expf(-absa * (float)cr);
    }
#pragma unroll
    for (int ni = 0; ni < 4; ++ni) {
        Epw[ni] = __expf(-absa * (float)(16 * (3 - ni)));
        Fpw[ni] = __expf(-absa * (float)(16 * ni));
    }
    const float Er = __expf(-absa * (float)ln16);
    const float Fr = __expf(-absa * (float)(15 - ln16));

    ffrag lacc = (ffrag){0.f, 0.f, 0.f, 0.f};
    ffrag o[4];
#pragma unroll
    for (int ni = 0; ni < 4; ++ni) o[ni] = (ffrag){0.f, 0.f, 0.f, 0.f};

    const int m = wave * 16 + ln16;

    for (int it = 0; it < ntiles; ++it) {
        const int t0 = (tlo + it) * 64;
        const int buf = it & 1;
        if (it + 1 < ntiles) stageKV(t0 + 64, buf ^ 1);   // async prefetch

        const ushort* Kt = &KVs[buf][0][0];
        const ushort* Vt = &KVs[buf][1][0];

        ffrag sc[4];
#pragma unroll
        for (int ni = 0; ni < 4; ++ni) {
            ffrag a = (ffrag){0.f, 0.f, 0.f, 0.f};
            const int rk = ni * 16 + ln16;
#pragma unroll
            for (int kb = 0; kb < 2; ++kb) {
                bfrag kf = *(const bfrag*)&Kt[rk * 64 + ((kb * 4 + quad + rk) & 7) * 8];
                a = mfma16(kf, aq[kb], a);
            }
            sc[ni] = a;
        }

        const int ds = q0 + wave * 16 - t0;
        float hh = 0.f;
        if (ds >= 64)       hh = __expf(-absa * (float)(ds - 63)) * Er * LOG2E;
        else if (ds <= -16) hh = __expf(-absa * (float)(-ds - 15)) * Fr * LOG2E;

#pragma unroll
        for (int ni = 0; ni < 4; ++ni) {
            float f0, f1, f2, f3;
            if (ds >= 64) {
                float hn = hh * Epw[ni];
                f0 = hn * EcB[0]; f1 = hn * EcB[1]; f2 = hn * EcB[2]; f3 = hn * EcB[3];
            } else if (ds <= -16) {
                float hn = hh * Fpw[ni];
                f0 = hn * FcB[0]; f1 = hn * FcB[1]; f2 = hn * FcB[2]; f3 = hn * FcB[3];
            } else {
                int c0 = ni * 16 + quad * 4;
                f0 = __expf(-absa * fabsf((float)(ds + ln16 - c0)))     * LOG2E;
                f1 = __expf(-absa * fabsf((float)(ds + ln16 - c0 - 1))) * LOG2E;
                f2 = __expf(-absa * fabsf((float)(ds + ln16 - c0 - 2))) * LOG2E;
                f3 = __expf(-absa * fabsf((float)(ds + ln16 - c0 - 3))) * LOG2E;
            }
            float p0 = exp2f(fmaf(sc[ni][0], f0, M0L2));
            float p1 = exp2f(fmaf(sc[ni][1], f1, M0L2));
            float p2 = exp2f(fmaf(sc[ni][2], f2, M0L2));
            float p3 = exp2f(fmaf(sc[ni][3], f3, M0L2));
            uint2 pk;
            pk.x = pkbf2(p0, p1);
            pk.y = pkbf2(p2, p3);
            *(uint2*)&Pb[m][ni * 16 + quad * 4] = pk;   // own-wave rows: no barrier
        }

        bfrag ap[2];
#pragma unroll
        for (int kb = 0; kb < 2; ++kb)
            ap[kb] = *(const bfrag*)&Pb[m][kb * 32 + quad * 8];

#pragma unroll
        for (int kb = 0; kb < 2; ++kb)
            lacc = mfma16(ones, ap[kb], lacc);
#pragma unroll
        for (int ni = 0; ni < 4; ++ni) {
            const int rv = ni * 16 + ln16;
#pragma unroll
            for (int kb = 0; kb < 2; ++kb) {
                bfrag vf = *(const bfrag*)&Vt[rv * 64 + ((kb * 4 + quad + rv) & 7) * 8];
                o[ni] = mfma16(vf, ap[kb], o[ni]);
            }
        }
        __syncthreads();
    }

    const float farl = E12 * (float)(SDIM - 64 * ntiles);
    const float inv = 1.f / (lacc[0] + farl);
    const int b = bh / HN, h = bh % HN;
    const int s = q0 + m;
    ushort* dst = Ob + ((size_t)(b * SDIM + s)) * EDIM + h * DDIM + quad * 4;
#pragma unroll
    for (int ni = 0; ni < 4; ++ni) {
        int d0 = ni * 16 + quad * 4;
        float v0 = (o[ni][0] + E12 * Fv[d0 + 0]) * inv;
        float v1 = (o[ni][1] + E12 * Fv[d0 + 1]) * inv;
        float v2 = (o[ni][2] + E12 * Fv[d0 + 2]) * inv;
        float v3 = (o[ni][3] + E12 * Fv[d0 + 3]) * inv;
        uint2 pk;
        pk.x = pkbf2(v0, v1);
        pk.y = pkbf2(v2, v3);
        *(uint2*)(dst + ni * 16) = pk;
    }
}

extern "C" void kernel_launch(void* const* d_in, const int* in_sizes, int n_in,
                              void* d_out, int out_size, void* d_ws, size_t ws_size,
                              hipStream_t stream) {
    const float* x      = (const float*)d_in[0];
    const float* Wqkv_w = (const float*)d_in[1];
    const float* Wqkv_b = (const float*)d_in[2];
    const float* out_w  = (const float*)d_in[3];
    const float* out_b  = (const float*)d_in[4];
    const float* dd     = (const float*)d_in[5];

    char* ws = (char*)d_ws;
    const size_t MB = 1024 * 1024;
    ushort* xb    = (ushort*)(ws + 0 * MB);    // dead after gemm256; T reuses it
    ushort* wqkvb = (ushort*)(ws + 8 * MB);
    ushort* owb   = (ushort*)(ws + 14 * MB);
    ushort* qkvb  = (ushort*)(ws + 16 * MB);   // q,k:[b,h,s,d] v:[b,h,d,s]
    ushort* ob    = (ushort*)(ws + 40 * MB);
    float*  Tp    = (float*)(ws + 0 * MB);     // 32*32*64*4 = 256 KB (after gemm256)

    const int n_x = BN * SDIM * EDIM;
    const int n_w = 3 * EDIM * EDIM;
    const int n_o = EDIM * EDIM;
    const int HSD = BN * HN * SDIM * DDIM;

    to_bf16_3<<<(n_x + n_w + n_o) / 1024, 256, 0, stream>>>(
        x, xb, n_x, Wqkv_w, wqkvb, n_w, out_w, owb, n_o);

    gemm256_qkv<0><<<dim3(16, 16), 512, 0, stream>>>(xb, wqkvb, Wqkv_b, qkvb,
                                                     BN * SDIM, 3 * EDIM, EDIM);

    vsum_tiles<<<dim3(32, 8), 256, 0, stream>>>(qkvb + 2 * HSD, Tp);

    flash_attn<<<dim3(SDIM / 128, BN * HN), 512, 0, stream>>>(
        qkvb, qkvb + HSD, qkvb + 2 * HSD, dd, Tp, ob);

    gemm128_op<<<dim3(32, 8), 512, 0, stream>>>(ob, owb, out_b, (float*)d_out,
                                                BN * SDIM, EDIM, EDIM);
}

// Round 7
// 157.821 us; speedup vs baseline: 1.0936x; 1.0447x over previous
//
#include <hip/hip_runtime.h>
#include <hip/hip_bf16.h>

#define BN 2
#define SDIM 2048
#define EDIM 1024
#define HN 16
#define DDIM 64

typedef __attribute__((ext_vector_type(8))) short bfrag;
typedef __attribute__((ext_vector_type(4))) float ffrag;

__device__ __forceinline__ ffrag mfma16(bfrag a, bfrag b, ffrag c) {
    return __builtin_amdgcn_mfma_f32_16x16x32_bf16(a, b, c, 0, 0, 0);
}

__device__ __forceinline__ ushort f2bf(float f) {
    union { float f; unsigned u; } un;
    un.f = f;
    unsigned u = un.u;
    u += 0x7fffu + ((u >> 16) & 1u);   // RNE
    return (ushort)(u >> 16);
}

__device__ __forceinline__ uint pkbf2(float a, float b) {
    __hip_bfloat162 h = __float22bfloat162_rn(make_float2(a, b));
    union { __hip_bfloat162 h; uint u; } cv;
    cv.h = h;
    return cv.u;
}

// async global->LDS: 16B/lane; LDS dest = wave-uniform base + lane*16
__device__ __forceinline__ void gld16(const void* g, void* l) {
    __builtin_amdgcn_global_load_lds((const __attribute__((address_space(1))) void*)g,
                                     (__attribute__((address_space(3))) void*)l,
                                     16, 0, 0);
}

// ---------------- fused fp32 -> bf16 conversion ----------------
__global__ __launch_bounds__(256) void to_bf16_3(const float* __restrict__ a, ushort* __restrict__ oa, int na,
                                                 const float* __restrict__ b, ushort* __restrict__ ob, int nb,
                                                 const float* __restrict__ c, ushort* __restrict__ oc, int nc) {
    int i = (blockIdx.x * 256 + threadIdx.x) * 4;
    const float* src;
    ushort* dst;
    if (i < na)                { src = a + i;            dst = oa + i; }
    else if (i < na + nb)      { src = b + (i - na);     dst = ob + (i - na); }
    else if (i < na + nb + nc) { src = c + (i - na - nb); dst = oc + (i - na - nb); }
    else return;
    float4 v = *(const float4*)src;
    uint2 u;
    u.x = pkbf2(v.x, v.y);
    u.y = pkbf2(v.z, v.w);
    *(uint2*)dst = u;
}

// ---------------- QKV GEMM: 128x192 tile, 2 blocks/CU, counted-vmcnt ----------------
// 8 waves (2M x 4N), wave tile 64x48, acc[4][3]. LDS: 2 bufs x (A 128x64 + B 192x64) = 80 KiB
// -> 2 blocks/CU = 16 waves/CU (cross-block TLP hides per-phase latency; R4 PMC showed
// 1-block/CU config at MfmaUtil 18.5%).
// Staging rounds (1 gld16/thread, 64 rows each): A.r0,A.r1 (rows wm*64), B.r0..r2.
// Issue schedule, iter t reading buf=t&1 (deadness: buf's B region dead after t.p0's
// lgkm-drain+barrier; buf^1 regions not yet holding t+1 data are free):
//   p0: t+1.A0 -> buf^1      p1: t+1.A1 -> buf^1, t+2.B0 -> buf
//   p2: t+2.B1 -> buf        p3: t+2.B2 -> buf
// Wait audit (steady state, p3-end queue oldest->newest):
//   [t+1.B0,B1,B2 (from t-1), t+1.A0, t+1.A1, t+2.B0, t+2.B1, t+2.B2] = 8
//   vmcnt(3) completes through t+1.A1 -> t+1 fully landed; t+2.B x3 stay in flight.
//   B gets ~7 phases issue-to-wait cover, A gets 3-4. Tail: t=nt-2 -> vmcnt(0); nt-1: none.
// Epilogue: qkv scatter + shuffle-based V tile-sums (no atomics/LDS/barriers).
// XCD swizzle: 8x8 panel cluster per XCD (bijective; grid 32x16, hw rr = lid%8).
template <int UNUSED>
__global__ __launch_bounds__(512, 4) void gemm192_qkv(const ushort* __restrict__ A,
                                                      const ushort* __restrict__ Bt,
                                                      const float* __restrict__ bias,
                                                      ushort* __restrict__ Cout,
                                                      float* __restrict__ T,
                                                      int M, int N, int K) {
    constexpr int BM = 128, BNT = 192;
    constexpr int A_USH = BM * 64;           // 8192
    constexpr int B_USH = BNT * 64;          // 12288
    constexpr int BUF_USH = A_USH + B_USH;   // 20480
    __shared__ ushort lds[2 * BUF_USH];      // 80 KiB -> 2 blocks/CU

    const int tid  = threadIdx.x;
    const int wave = tid >> 6;
    const int lane = tid & 63;
    const int ln16 = lane & 15;
    const int quad = lane >> 4;
    const int wm   = wave >> 2;              // 0..1
    const int wn   = wave & 3;               // 0..3

    // XCD-aware bijective swizzle: grid 32x16 -> 512 blocks, 64/XCD = 8 A-panels x 8 B-panels
    const int lid  = blockIdx.y * 32 + blockIdx.x;
    const int xcd  = lid & 7;
    const int rank = lid >> 3;               // 0..63
    const int tx   = (xcd & 3) * 8 + (rank & 7);    // 0..31
    const int ty   = (xcd >> 2) * 8 + (rank >> 3);  // 0..15
    const int bm   = tx * BM;
    const int bn   = ty * BNT;

    const int r0 = tid >> 3;                 // 0..63
    const int c0 = ((tid & 7) - r0) & 7;     // inverse rotate swizzle
    const ushort* Abase = A  + (size_t)(bm + r0) * K + c0 * 8;
    const ushort* Bbase = Bt + (size_t)(bn + r0) * K + c0 * 8;
    const int ldst0 = wave * 512;            // wave-uniform chunk base within round

    const int Ra = wm * 64 + ln16;           // row mod 8 invariant across mi
    const int Rb = wn * 48 + ln16;
    int aoff[2], boff[2];
#pragma unroll
    for (int kb = 0; kb < 2; ++kb) {
        aoff[kb] = Ra * 64 + ((kb * 4 + quad + Ra) & 7) * 8;
        boff[kb] = A_USH + Rb * 64 + ((kb * 4 + quad + Rb) & 7) * 8;
    }

    ffrag acc[4][3];
#pragma unroll
    for (int mi = 0; mi < 4; ++mi)
#pragma unroll
        for (int ni = 0; ni < 3; ++ni)
            acc[mi][ni] = (ffrag){0.f, 0.f, 0.f, 0.f};

    const int nt = K >> 6;                   // 16

    auto stA = [&](int buf, int t, int rnd) {
        gld16(Abase + (size_t)rnd * 64 * K + t * 64,
              &lds[buf * BUF_USH + rnd * 4096 + ldst0]);
    };
    auto stB = [&](int buf, int t, int rnd) {
        gld16(Bbase + (size_t)rnd * 64 * K + t * 64,
              &lds[buf * BUF_USH + A_USH + rnd * 4096 + ldst0]);
    };

    // prologue: tile0 full (5) -> buf0; tile1 B-rounds (3) -> buf1
    stA(0, 0, 0); stA(0, 0, 1);
    stB(0, 0, 0); stB(0, 0, 1); stB(0, 0, 2);
    stB(1, 1, 0); stB(1, 1, 1); stB(1, 1, 2);
    asm volatile("s_waitcnt vmcnt(3)" ::: "memory");
    __builtin_amdgcn_s_barrier();

    for (int t = 0; t < nt; ++t) {
        const int buf = t & 1;
        const ushort* Al = &lds[buf * BUF_USH];
        const bool h1 = (t + 1) < nt;
        const bool h2 = (t + 2) < nt;
        bfrag bfr[3][2];
#pragma unroll
        for (int p = 0; p < 4; ++p) {
            bfrag afr[2];
#pragma unroll
            for (int kb = 0; kb < 2; ++kb)
                afr[kb] = *(const bfrag*)(Al + aoff[kb] + p * 1024);
            if (p == 0) {
#pragma unroll
                for (int ni = 0; ni < 3; ++ni)
#pragma unroll
                    for (int kb = 0; kb < 2; ++kb)
                        bfr[ni][kb] = *(const bfrag*)(Al + boff[kb] + ni * 1024);
            }
            if (p == 0 && h1) stA(buf ^ 1, t + 1, 0);
            if (p == 1 && h1) stA(buf ^ 1, t + 1, 1);
            if (p == 1 && h2) stB(buf, t + 2, 0);
            if (p == 2 && h2) stB(buf, t + 2, 1);
            if (p == 3 && h2) stB(buf, t + 2, 2);

            __builtin_amdgcn_s_barrier();
            asm volatile("s_waitcnt lgkmcnt(0)" ::: "memory");
            __builtin_amdgcn_sched_barrier(0);
            __builtin_amdgcn_s_setprio(1);
#pragma unroll
            for (int ni = 0; ni < 3; ++ni)
#pragma unroll
                for (int kb = 0; kb < 2; ++kb)
                    acc[p][ni] = mfma16(afr[kb], bfr[ni][kb], acc[p][ni]);
            __builtin_amdgcn_s_setprio(0);
            if (p == 3) {
                if (h2)      { asm volatile("s_waitcnt vmcnt(3)" ::: "memory"); }
                else if (h1) { asm volatile("s_waitcnt vmcnt(0)" ::: "memory"); }
            }
            __builtin_amdgcn_s_barrier();
        }
    }

    // epilogue: qkv scatter (q scaled 1/8, V transposed to [b,h,d,s])
#pragma unroll
    for (int mi = 0; mi < 4; ++mi) {
#pragma unroll
        for (int ni = 0; ni < 3; ++ni) {
            int col = bn + wn * 48 + ni * 16 + ln16;
            float bc = bias[col];
            int row0 = bm + wm * 64 + mi * 16 + quad * 4;
            int which = col >> 10;
            int rem = col & 1023;
            int h = rem >> 6;
            int d = rem & 63;
            int b = row0 >> 11;
            int s0 = row0 & 2047;
            if (which == 2) {
                float v0 = acc[mi][ni][0] + bc, v1 = acc[mi][ni][1] + bc;
                float v2 = acc[mi][ni][2] + bc, v3 = acc[mi][ni][3] + bc;
                uint2 pk;
                pk.x = pkbf2(v0, v1);
                pk.y = pkbf2(v2, v3);
                size_t dst = 2ull * (BN * HN * SDIM * DDIM) +
                             (((size_t)(b * HN + h)) * DDIM + d) * SDIM + s0;
                *(uint2*)(Cout + dst) = pk;
            } else {
                float sc = (which == 0) ? 0.125f : 1.f;
#pragma unroll
                for (int reg = 0; reg < 4; ++reg) {
                    float v = (acc[mi][ni][reg] + bc) * sc;
                    size_t dst = (size_t)which * (BN * HN * SDIM * DDIM) +
                                 (((size_t)(b * HN + h)) * SDIM + s0 + reg) * DDIM + d;
                    Cout[dst] = f2bf(v);
                }
            }
        }
    }

    // V tile-sums via quad-shuffle reduction (each wave owns exactly one 64-row s-tile:
    // tl = wm; rows covered by mi x quad x reg = 64). No atomics, no barriers.
#pragma unroll
    for (int ni = 0; ni < 3; ++ni) {
        int col = bn + wn * 48 + ni * 16 + ln16;
        if ((col >> 10) == 2) {              // wave-uniform per ni (16-aligned groups)
            float s = 0.f;
#pragma unroll
            for (int mi = 0; mi < 4; ++mi)
#pragma unroll
                for (int reg = 0; reg < 4; ++reg)
                    s += acc[mi][ni][reg];
            s += __shfl_xor(s, 16);          // reduce across quad (lanes ln16 + q*16)
            s += __shfl_xor(s, 32);
            if (quad == 0) {
                float bc = bias[col];
                int rem = col & 1023;
                int h = rem >> 6, d = rem & 63;
                int b = bm >> 11;
                int tile_g = ((bm & 2047) >> 6) + wm;   // 0..31
                T[(((size_t)(b * HN + h)) * 32 + tile_g) * 64 + d] = s + 64.f * bc;
            }
        }
    }
}

// ---------------- out-projection GEMM: 128x128 tile, 2-phase counted-vmcnt ----------------
// 8 waves (2M x 4N), wave tile 64x32, acc[4][2]. LDS: 2 bufs x (A 128x64 + B 128x64) = 64 KiB
// -> 2 blocks/CU (16 waves/CU). Per K-tile: 4 staging rounds (A.r0,A.r1,B.r0,B.r1).
__global__ __launch_bounds__(512, 4) void gemm128_op(const ushort* __restrict__ A,
                                                     const ushort* __restrict__ Bt,
                                                     const float* __restrict__ bias,
                                                     float* __restrict__ C,
                                                     int M, int N, int K) {
    constexpr int BM = 128, BNT = 128;
    constexpr int A_USH = BM * 64;           // 8192
    constexpr int B_USH = BNT * 64;          // 8192
    constexpr int BUF_USH = A_USH + B_USH;   // 16384
    __shared__ ushort lds[2 * BUF_USH];      // 64 KiB

    const int tid  = threadIdx.x;
    const int wave = tid >> 6;
    const int lane = tid & 63;
    const int ln16 = lane & 15;
    const int quad = lane >> 4;
    const int wm   = wave >> 2;              // 0..1
    const int wn   = wave & 3;               // 0..3
    const int bm   = blockIdx.x * BM;
    const int bn   = blockIdx.y * BNT;

    const int r0 = tid >> 3;                 // 0..63 (row within 64-row round)
    const int c0 = ((tid & 7) - r0) & 7;     // inverse rotate swizzle
    const ushort* Abase = A  + (size_t)(bm + r0) * K + c0 * 8;
    const ushort* Bbase = Bt + (size_t)(bn + r0) * K + c0 * 8;
    const int ldst0 = wave * 512;

    const int Ra = wm * 64 + ln16;
    const int Rb = wn * 32 + ln16;
    int aoff[2], boff[2];
#pragma unroll
    for (int kb = 0; kb < 2; ++kb) {
        aoff[kb] = Ra * 64 + ((kb * 4 + quad + Ra) & 7) * 8;
        boff[kb] = A_USH + Rb * 64 + ((kb * 4 + quad + Rb) & 7) * 8;
    }

    ffrag acc[4][2];
#pragma unroll
    for (int mi = 0; mi < 4; ++mi)
#pragma unroll
        for (int ni = 0; ni < 2; ++ni)
            acc[mi][ni] = (ffrag){0.f, 0.f, 0.f, 0.f};

    const int nt = K >> 6;                   // 16

    auto stA = [&](int buf, int t, int rnd) {
        gld16(Abase + (size_t)rnd * 64 * K + t * 64,
              &lds[buf * BUF_USH + rnd * 4096 + ldst0]);
    };
    auto stB = [&](int buf, int t, int rnd) {
        gld16(Bbase + (size_t)rnd * 64 * K + t * 64,
              &lds[buf * BUF_USH + A_USH + rnd * 4096 + ldst0]);
    };

    // prologue: tile0 -> buf0, tile1 -> buf1; wait tile0 (4 newest stay in flight)
    stA(0, 0, 0); stA(0, 0, 1); stB(0, 0, 0); stB(0, 0, 1);
    stA(1, 1, 0); stA(1, 1, 1); stB(1, 1, 0); stB(1, 1, 1);
    asm volatile("s_waitcnt vmcnt(4)" ::: "memory");
    __builtin_amdgcn_s_barrier();

    for (int t = 0; t < nt; ++t) {
        const int buf = t & 1;
        const ushort* Al = &lds[buf * BUF_USH];
        bfrag afr[4][2], bfr[2][2];
#pragma unroll
        for (int mi = 0; mi < 4; ++mi)
#pragma unroll
            for (int kb = 0; kb < 2; ++kb)
                afr[mi][kb] = *(const bfrag*)(Al + aoff[kb] + mi * 1024);
#pragma unroll
        for (int ni = 0; ni < 2; ++ni)
#pragma unroll
            for (int kb = 0; kb < 2; ++kb)
                bfr[ni][kb] = *(const bfrag*)(Al + boff[kb] + ni * 1024);
        asm volatile("s_waitcnt lgkmcnt(0)" ::: "memory");
        __builtin_amdgcn_sched_barrier(0);
        __builtin_amdgcn_s_barrier();        // barrier1: every wave's reads drained

        if (t + 2 < nt) {                    // stage t+2 into the now-dead current buf
            stA(buf, t + 2, 0); stA(buf, t + 2, 1);
            stB(buf, t + 2, 0); stB(buf, t + 2, 1);
        }

        __builtin_amdgcn_s_setprio(1);
#pragma unroll
        for (int mi = 0; mi < 4; ++mi)
#pragma unroll
            for (int ni = 0; ni < 2; ++ni)
#pragma unroll
                for (int kb = 0; kb < 2; ++kb)
                    acc[mi][ni] = mfma16(afr[mi][kb], bfr[ni][kb], acc[mi][ni]);
        __builtin_amdgcn_s_setprio(0);

        if (t + 2 < nt)      { asm volatile("s_waitcnt vmcnt(4)" ::: "memory"); }
        else if (t + 1 < nt) { asm volatile("s_waitcnt vmcnt(0)" ::: "memory"); }
        __builtin_amdgcn_s_barrier();        // barrier2: next tile ready
    }

    // epilogue: fp32 row-major + bias
#pragma unroll
    for (int mi = 0; mi < 4; ++mi) {
#pragma unroll
        for (int ni = 0; ni < 2; ++ni) {
            int col = bn + wn * 32 + ni * 16 + ln16;
            float bc = bias[col];
            int row0 = bm + wm * 64 + mi * 16 + quad * 4;
#pragma unroll
            for (int reg = 0; reg < 4; ++reg)
                C[(size_t)(row0 + reg) * N + col] = acc[mi][ni][reg] + bc;
        }
    }
}

// ---------------- flash attention with near-band + closed-form far field ----------------
__global__ __launch_bounds__(512, 4) void flash_attn(const ushort* __restrict__ Qb,
                                                     const ushort* __restrict__ Kb,
                                                     const ushort* __restrict__ Vtb,
                                                     const float* __restrict__ decay_ptr,
                                                     const float* __restrict__ T,
                                                     ushort* __restrict__ Ob) {
    __shared__ ushort KVs[2][2][4096];   // [buf][K / Vt][64 rows x 8 chunks, swizzled]
    __shared__ ushort Pb[128][72];       // Q staging, then P exchange (per-wave rows)
    __shared__ float  Fv[64];            // far-field V sum per d

    const int tid  = threadIdx.x;
    const int wave = tid >> 6;
    const int lane = tid & 63;
    const int ln16 = lane & 15;
    const int quad = lane >> 4;

    const int bh = blockIdx.y;
    const int q0 = blockIdx.x * 128;
    const size_t head_off = (size_t)bh * SDIM * DDIM;
    const float absa = fabsf(decay_ptr[0]);
    const float LOG2E = 1.442695041f;
    const float M0L2 = -17.3123404f;     // -12 * log2(e)
    const float E12 = 6.144212353e-6f;   // e^-12

    int Dstar = (absa > 1e-5f) ? (int)ceilf(16.0f / absa) : (4 * SDIM);
    int lo = q0 - 63 - Dstar; if (lo < 0) lo = 0;
    int hi = q0 + 127 + Dstar; if (hi > SDIM - 1) hi = SDIM - 1;
    const int tlo = lo >> 6;
    const int thi = hi >> 6;
    const int ntiles = thi - tlo + 1;

    if (tid < 64) {
        const float* Tp = T + (size_t)bh * 32 * 64;
        float s = 0.f;
        for (int k = 0; k < tlo; ++k)      s += Tp[k * 64 + tid];
        for (int k = thi + 1; k < 32; ++k) s += Tp[k * 64 + tid];
        Fv[tid] = s;
    }

    auto stageKV = [&](int t0, int buf) {
        int g0 = wave * 64;
        int g  = g0 + lane;
        int r  = g >> 3;
        int c  = (g - r) & 7;            // inverse swizzle
        gld16(Kb  + head_off + (size_t)(t0 + r) * DDIM + c * 8,
              (ushort*)&KVs[buf][0][0] + g0 * 8);
        gld16(Vtb + head_off + (size_t)r * SDIM + t0 + c * 8,
              (ushort*)&KVs[buf][1][0] + g0 * 8);
    };

#pragma unroll
    for (int p = 0; p < 2; ++p) {
        int idx = p * 512 + tid;
        int r = idx >> 3, c = (idx & 7) * 8;
        *(uint4*)&Pb[r][c] = *(const uint4*)(Qb + head_off + (size_t)(q0 + r) * DDIM + c);
    }
    stageKV(tlo * 64, 0);
    __syncthreads();

    bfrag aq[2];
#pragma unroll
    for (int kb = 0; kb < 2; ++kb)
        aq[kb] = *(const bfrag*)&Pb[wave * 16 + ln16][kb * 32 + quad * 8];

    bfrag ones;
#pragma unroll
    for (int i = 0; i < 8; ++i) ones[i] = (short)0x3F80;   // bf16 1.0

    float EcB[4], FcB[4], Epw[4], Fpw[4];
#pragma unroll
    for (int reg = 0; reg < 4; ++reg) {
        int cr = quad * 4 + reg;
        EcB[reg] = __expf(-absa * (float)(15 - cr));
        FcB[reg] = __expf(-absa * (float)cr);
    }
#pragma unroll
    for (int ni = 0; ni < 4; ++ni) {
        Epw[ni] = __expf(-absa * (float)(16 * (3 - ni)));
        Fpw[ni] = __expf(-absa * (float)(16 * ni));
    }
    const float Er = __expf(-absa * (float)ln16);
    const float Fr = __expf(-absa * (float)(15 - ln16));

    ffrag lacc = (ffrag){0.f, 0.f, 0.f, 0.f};
    ffrag o[4];
#pragma unroll
    for (int ni = 0; ni < 4; ++ni) o[ni] = (ffrag){0.f, 0.f, 0.f, 0.f};

    const int m = wave * 16 + ln16;

    for (int it = 0; it < ntiles; ++it) {
        const int t0 = (tlo + it) * 64;
        const int buf = it & 1;
        if (it + 1 < ntiles) stageKV(t0 + 64, buf ^ 1);   // async prefetch

        const ushort* Kt = &KVs[buf][0][0];
        const ushort* Vt = &KVs[buf][1][0];

        ffrag sc[4];
#pragma unroll
        for (int ni = 0; ni < 4; ++ni) {
            ffrag a = (ffrag){0.f, 0.f, 0.f, 0.f};
            const int rk = ni * 16 + ln16;
#pragma unroll
            for (int kb = 0; kb < 2; ++kb) {
                bfrag kf = *(const bfrag*)&Kt[rk * 64 + ((kb * 4 + quad + rk) & 7) * 8];
                a = mfma16(kf, aq[kb], a);
            }
            sc[ni] = a;
        }

        const int ds = q0 + wave * 16 - t0;
        float hh = 0.f;
        if (ds >= 64)       hh = __expf(-absa * (float)(ds - 63)) * Er * LOG2E;
        else if (ds <= -16) hh = __expf(-absa * (float)(-ds - 15)) * Fr * LOG2E;

#pragma unroll
        for (int ni = 0; ni < 4; ++ni) {
            float f0, f1, f2, f3;
            if (ds >= 64) {
                float hn = hh * Epw[ni];
                f0 = hn * EcB[0]; f1 = hn * EcB[1]; f2 = hn * EcB[2]; f3 = hn * EcB[3];
            } else if (ds <= -16) {
                float hn = hh * Fpw[ni];
                f0 = hn * FcB[0]; f1 = hn * FcB[1]; f2 = hn * FcB[2]; f3 = hn * FcB[3];
            } else {
                int c0 = ni * 16 + quad * 4;
                f0 = __expf(-absa * fabsf((float)(ds + ln16 - c0)))     * LOG2E;
                f1 = __expf(-absa * fabsf((float)(ds + ln16 - c0 - 1))) * LOG2E;
                f2 = __expf(-absa * fabsf((float)(ds + ln16 - c0 - 2))) * LOG2E;
                f3 = __expf(-absa * fabsf((float)(ds + ln16 - c0 - 3))) * LOG2E;
            }
            float p0 = exp2f(fmaf(sc[ni][0], f0, M0L2));
            float p1 = exp2f(fmaf(sc[ni][1], f1, M0L2));
            float p2 = exp2f(fmaf(sc[ni][2], f2, M0L2));
            float p3 = exp2f(fmaf(sc[ni][3], f3, M0L2));
            uint2 pk;
            pk.x = pkbf2(p0, p1);
            pk.y = pkbf2(p2, p3);
            *(uint2*)&Pb[m][ni * 16 + quad * 4] = pk;   // own-wave rows: no barrier
        }

        bfrag ap[2];
#pragma unroll
        for (int kb = 0; kb < 2; ++kb)
            ap[kb] = *(const bfrag*)&Pb[m][kb * 32 + quad * 8];

#pragma unroll
        for (int kb = 0; kb < 2; ++kb)
            lacc = mfma16(ones, ap[kb], lacc);
#pragma unroll
        for (int ni = 0; ni < 4; ++ni) {
            const int rv = ni * 16 + ln16;
#pragma unroll
            for (int kb = 0; kb < 2; ++kb) {
                bfrag vf = *(const bfrag*)&Vt[rv * 64 + ((kb * 4 + quad + rv) & 7) * 8];
                o[ni] = mfma16(vf, ap[kb], o[ni]);
            }
        }
        __syncthreads();
    }

    const float farl = E12 * (float)(SDIM - 64 * ntiles);
    const float inv = 1.f / (lacc[0] + farl);
    const int b = bh / HN, h = bh % HN;
    const int s = q0 + m;
    ushort* dst = Ob + ((size_t)(b * SDIM + s)) * EDIM + h * DDIM + quad * 4;
#pragma unroll
    for (int ni = 0; ni < 4; ++ni) {
        int d0 = ni * 16 + quad * 4;
        float v0 = (o[ni][0] + E12 * Fv[d0 + 0]) * inv;
        float v1 = (o[ni][1] + E12 * Fv[d0 + 1]) * inv;
        float v2 = (o[ni][2] + E12 * Fv[d0 + 2]) * inv;
        float v3 = (o[ni][3] + E12 * Fv[d0 + 3]) * inv;
        uint2 pk;
        pk.x = pkbf2(v0, v1);
        pk.y = pkbf2(v2, v3);
        *(uint2*)(dst + ni * 16) = pk;
    }
}

extern "C" void kernel_launch(void* const* d_in, const int* in_sizes, int n_in,
                              void* d_out, int out_size, void* d_ws, size_t ws_size,
                              hipStream_t stream) {
    const float* x      = (const float*)d_in[0];
    const float* Wqkv_w = (const float*)d_in[1];
    const float* Wqkv_b = (const float*)d_in[2];
    const float* out_w  = (const float*)d_in[3];
    const float* out_b  = (const float*)d_in[4];
    const float* dd     = (const float*)d_in[5];

    char* ws = (char*)d_ws;
    const size_t MB = 1024 * 1024;
    ushort* xb    = (ushort*)(ws + 0 * MB);
    ushort* wqkvb = (ushort*)(ws + 8 * MB);
    ushort* owb   = (ushort*)(ws + 14 * MB);
    ushort* qkvb  = (ushort*)(ws + 16 * MB);   // q,k:[b,h,s,d] v:[b,h,d,s]
    ushort* ob    = (ushort*)(ws + 40 * MB);
    float*  Tp    = (float*)(ws + 48 * MB);    // own slab (gemm epilogue writes while xb live)

    const int n_x = BN * SDIM * EDIM;
    const int n_w = 3 * EDIM * EDIM;
    const int n_o = EDIM * EDIM;
    const int HSD = BN * HN * SDIM * DDIM;

    to_bf16_3<<<(n_x + n_w + n_o) / 1024, 256, 0, stream>>>(
        x, xb, n_x, Wqkv_w, wqkvb, n_w, out_w, owb, n_o);

    gemm192_qkv<0><<<dim3(32, 16), 512, 0, stream>>>(xb, wqkvb, Wqkv_b, qkvb, Tp,
                                                     BN * SDIM, 3 * EDIM, EDIM);

    flash_attn<<<dim3(SDIM / 128, BN * HN), 512, 0, stream>>>(
        qkvb, qkvb + HSD, qkvb + 2 * HSD, dd, Tp, ob);

    gemm128_op<<<dim3(32, 8), 512, 0, stream>>>(ob, owb, out_b, (float*)d_out,
                                                BN * SDIM, EDIM, EDIM);
}

// Round 8
// 156.625 us; speedup vs baseline: 1.1020x; 1.0076x over previous
//
#include <hip/hip_runtime.h>
#include <hip/hip_bf16.h>

#define BN 2
#define SDIM 2048
#define EDIM 1024
#define HN 16
#define DDIM 64

typedef __attribute__((ext_vector_type(8))) short bfrag;
typedef __attribute__((ext_vector_type(4))) float ffrag;

__device__ __forceinline__ ffrag mfma16(bfrag a, bfrag b, ffrag c) {
    return __builtin_amdgcn_mfma_f32_16x16x32_bf16(a, b, c, 0, 0, 0);
}

__device__ __forceinline__ ushort f2bf(float f) {
    union { float f; unsigned u; } un;
    un.f = f;
    unsigned u = un.u;
    u += 0x7fffu + ((u >> 16) & 1u);   // RNE
    return (ushort)(u >> 16);
}

__device__ __forceinline__ uint pkbf2(float a, float b) {
    __hip_bfloat162 h = __float22bfloat162_rn(make_float2(a, b));
    union { __hip_bfloat162 h; uint u; } cv;
    cv.h = h;
    return cv.u;
}

// async global->LDS: 16B/lane; LDS dest = wave-uniform base + lane*16
__device__ __forceinline__ void gld16(const void* g, void* l) {
    __builtin_amdgcn_global_load_lds((const __attribute__((address_space(1))) void*)g,
                                     (__attribute__((address_space(3))) void*)l,
                                     16, 0, 0);
}

// ---------------- fused fp32 -> bf16 conversion ----------------
__global__ __launch_bounds__(256) void to_bf16_3(const float* __restrict__ a, ushort* __restrict__ oa, int na,
                                                 const float* __restrict__ b, ushort* __restrict__ ob, int nb,
                                                 const float* __restrict__ c, ushort* __restrict__ oc, int nc) {
    int i = (blockIdx.x * 256 + threadIdx.x) * 4;
    const float* src;
    ushort* dst;
    if (i < na)                { src = a + i;            dst = oa + i; }
    else if (i < na + nb)      { src = b + (i - na);     dst = ob + (i - na); }
    else if (i < na + nb + nc) { src = c + (i - na - nb); dst = oc + (i - na - nb); }
    else return;
    float4 v = *(const float4*)src;
    uint2 u;
    u.x = pkbf2(v.x, v.y);
    u.y = pkbf2(v.z, v.w);
    *(uint2*)dst = u;
}

// ---------------- QKV GEMM: 128x192 tile, 2 blocks/CU, counted-vmcnt ----------------
// 8 waves (2M x 4N), wave tile 64x48, acc[4][3]. LDS: 2 bufs x (A 128x64 + B 192x64) = 80 KiB
// -> 2 blocks/CU = 16 waves/CU (cross-block TLP hides per-phase latency; R4 PMC showed
// 1-block/CU config at MfmaUtil 18.5%).
// Staging rounds (1 gld16/thread, 64 rows each): A.r0,A.r1 (rows wm*64), B.r0..r2.
// Issue schedule, iter t reading buf=t&1 (deadness: buf's B region dead after t.p0's
// lgkm-drain+barrier; buf^1 regions not yet holding t+1 data are free):
//   p0: t+1.A0 -> buf^1      p1: t+1.A1 -> buf^1, t+2.B0 -> buf
//   p2: t+2.B1 -> buf        p3: t+2.B2 -> buf
// Wait audit (steady state, p3-end queue oldest->newest):
//   [t+1.B0,B1,B2 (from t-1), t+1.A0, t+1.A1, t+2.B0, t+2.B1, t+2.B2] = 8
//   vmcnt(3) completes through t+1.A1 -> t+1 fully landed; t+2.B x3 stay in flight.
//   B gets ~7 phases issue-to-wait cover, A gets 3-4. Tail: t=nt-2 -> vmcnt(0); nt-1: none.
// Epilogue: qkv scatter + shuffle-based V tile-sums (no atomics/LDS/barriers).
// XCD swizzle: 8x8 panel cluster per XCD (bijective; grid 32x16, hw rr = lid%8).
template <int UNUSED>
__global__ __launch_bounds__(512, 4) void gemm192_qkv(const ushort* __restrict__ A,
                                                      const ushort* __restrict__ Bt,
                                                      const float* __restrict__ bias,
                                                      ushort* __restrict__ Cout,
                                                      float* __restrict__ T,
                                                      int M, int N, int K) {
    constexpr int BM = 128, BNT = 192;
    constexpr int A_USH = BM * 64;           // 8192
    constexpr int B_USH = BNT * 64;          // 12288
    constexpr int BUF_USH = A_USH + B_USH;   // 20480
    __shared__ ushort lds[2 * BUF_USH];      // 80 KiB -> 2 blocks/CU

    const int tid  = threadIdx.x;
    const int wave = tid >> 6;
    const int lane = tid & 63;
    const int ln16 = lane & 15;
    const int quad = lane >> 4;
    const int wm   = wave >> 2;              // 0..1
    const int wn   = wave & 3;               // 0..3

    // XCD-aware bijective swizzle: grid 32x16 -> 512 blocks, 64/XCD = 8 A-panels x 8 B-panels
    const int lid  = blockIdx.y * 32 + blockIdx.x;
    const int xcd  = lid & 7;
    const int rank = lid >> 3;               // 0..63
    const int tx   = (xcd & 3) * 8 + (rank & 7);    // 0..31
    const int ty   = (xcd >> 2) * 8 + (rank >> 3);  // 0..15
    const int bm   = tx * BM;
    const int bn   = ty * BNT;

    const int r0 = tid >> 3;                 // 0..63
    const int c0 = ((tid & 7) - r0) & 7;     // inverse rotate swizzle
    const ushort* Abase = A  + (size_t)(bm + r0) * K + c0 * 8;
    const ushort* Bbase = Bt + (size_t)(bn + r0) * K + c0 * 8;
    const int ldst0 = wave * 512;            // wave-uniform chunk base within round

    const int Ra = wm * 64 + ln16;           // row mod 8 invariant across mi
    const int Rb = wn * 48 + ln16;
    int aoff[2], boff[2];
#pragma unroll
    for (int kb = 0; kb < 2; ++kb) {
        aoff[kb] = Ra * 64 + ((kb * 4 + quad + Ra) & 7) * 8;
        boff[kb] = A_USH + Rb * 64 + ((kb * 4 + quad + Rb) & 7) * 8;
    }

    ffrag acc[4][3];
#pragma unroll
    for (int mi = 0; mi < 4; ++mi)
#pragma unroll
        for (int ni = 0; ni < 3; ++ni)
            acc[mi][ni] = (ffrag){0.f, 0.f, 0.f, 0.f};

    const int nt = K >> 6;                   // 16

    auto stA = [&](int buf, int t, int rnd) {
        gld16(Abase + (size_t)rnd * 64 * K + t * 64,
              &lds[buf * BUF_USH + rnd * 4096 + ldst0]);
    };
    auto stB = [&](int buf, int t, int rnd) {
        gld16(Bbase + (size_t)rnd * 64 * K + t * 64,
              &lds[buf * BUF_USH + A_USH + rnd * 4096 + ldst0]);
    };

    // prologue: tile0 full (5) -> buf0; tile1 B-rounds (3) -> buf1
    stA(0, 0, 0); stA(0, 0, 1);
    stB(0, 0, 0); stB(0, 0, 1); stB(0, 0, 2);
    stB(1, 1, 0); stB(1, 1, 1); stB(1, 1, 2);
    asm volatile("s_waitcnt vmcnt(3)" ::: "memory");
    __builtin_amdgcn_s_barrier();

    for (int t = 0; t < nt; ++t) {
        const int buf = t & 1;
        const ushort* Al = &lds[buf * BUF_USH];
        const bool h1 = (t + 1) < nt;
        const bool h2 = (t + 2) < nt;
        bfrag bfr[3][2];
#pragma unroll
        for (int p = 0; p < 4; ++p) {
            bfrag afr[2];
#pragma unroll
            for (int kb = 0; kb < 2; ++kb)
                afr[kb] = *(const bfrag*)(Al + aoff[kb] + p * 1024);
            if (p == 0) {
#pragma unroll
                for (int ni = 0; ni < 3; ++ni)
#pragma unroll
                    for (int kb = 0; kb < 2; ++kb)
                        bfr[ni][kb] = *(const bfrag*)(Al + boff[kb] + ni * 1024);
            }
            if (p == 0 && h1) stA(buf ^ 1, t + 1, 0);
            if (p == 1 && h1) stA(buf ^ 1, t + 1, 1);
            if (p == 1 && h2) stB(buf, t + 2, 0);
            if (p == 2 && h2) stB(buf, t + 2, 1);
            if (p == 3 && h2) stB(buf, t + 2, 2);

            __builtin_amdgcn_s_barrier();
            asm volatile("s_waitcnt lgkmcnt(0)" ::: "memory");
            __builtin_amdgcn_sched_barrier(0);
            __builtin_amdgcn_s_setprio(1);
#pragma unroll
            for (int ni = 0; ni < 3; ++ni)
#pragma unroll
                for (int kb = 0; kb < 2; ++kb)
                    acc[p][ni] = mfma16(afr[kb], bfr[ni][kb], acc[p][ni]);
            __builtin_amdgcn_s_setprio(0);
            if (p == 3) {
                if (h2)      { asm volatile("s_waitcnt vmcnt(3)" ::: "memory"); }
                else if (h1) { asm volatile("s_waitcnt vmcnt(0)" ::: "memory"); }
            }
            __builtin_amdgcn_s_barrier();
        }
    }

    // epilogue: qkv scatter (q scaled 1/8, V transposed to [b,h,d,s])
#pragma unroll
    for (int mi = 0; mi < 4; ++mi) {
#pragma unroll
        for (int ni = 0; ni < 3; ++ni) {
            int col = bn + wn * 48 + ni * 16 + ln16;
            float bc = bias[col];
            int row0 = bm + wm * 64 + mi * 16 + quad * 4;
            int which = col >> 10;
            int rem = col & 1023;
            int h = rem >> 6;
            int d = rem & 63;
            int b = row0 >> 11;
            int s0 = row0 & 2047;
            if (which == 2) {
                float v0 = acc[mi][ni][0] + bc, v1 = acc[mi][ni][1] + bc;
                float v2 = acc[mi][ni][2] + bc, v3 = acc[mi][ni][3] + bc;
                uint2 pk;
                pk.x = pkbf2(v0, v1);
                pk.y = pkbf2(v2, v3);
                size_t dst = 2ull * (BN * HN * SDIM * DDIM) +
                             (((size_t)(b * HN + h)) * DDIM + d) * SDIM + s0;
                *(uint2*)(Cout + dst) = pk;
            } else {
                float sc = (which == 0) ? 0.125f : 1.f;
#pragma unroll
                for (int reg = 0; reg < 4; ++reg) {
                    float v = (acc[mi][ni][reg] + bc) * sc;
                    size_t dst = (size_t)which * (BN * HN * SDIM * DDIM) +
                                 (((size_t)(b * HN + h)) * SDIM + s0 + reg) * DDIM + d;
                    Cout[dst] = f2bf(v);
                }
            }
        }
    }

    // V tile-sums via quad-shuffle reduction (each wave owns exactly one 64-row s-tile:
    // tl = wm; rows covered by mi x quad x reg = 64). No atomics, no barriers.
#pragma unroll
    for (int ni = 0; ni < 3; ++ni) {
        int col = bn + wn * 48 + ni * 16 + ln16;
        if ((col >> 10) == 2) {              // wave-uniform per ni (16-aligned groups)
            float s = 0.f;
#pragma unroll
            for (int mi = 0; mi < 4; ++mi)
#pragma unroll
                for (int reg = 0; reg < 4; ++reg)
                    s += acc[mi][ni][reg];
            s += __shfl_xor(s, 16);          // reduce across quad (lanes ln16 + q*16)
            s += __shfl_xor(s, 32);
            if (quad == 0) {
                float bc = bias[col];
                int rem = col & 1023;
                int h = rem >> 6, d = rem & 63;
                int b = bm >> 11;
                int tile_g = ((bm & 2047) >> 6) + wm;   // 0..31
                T[(((size_t)(b * HN + h)) * 32 + tile_g) * 64 + d] = s + 64.f * bc;
            }
        }
    }
}

// ---------------- out-projection GEMM: 64x128 tile, 2 blocks/CU, counted-vmcnt ----------------
// Retiled from 128x128 (which ran at grid 256 = 1 block/CU, the exact no-TLP configuration
// R4's PMC indicted for gemm256: MfmaUtil 18.5%, all waves on one barrier cadence).
// 8 waves (2M x 4N), wave tile 32x32, acc[2][2]. LDS: 2 bufs x (A 64x64 + B 128x64) = 48 KiB
// -> grid (64,8) = 512 blocks = 2 blocks/CU (16 waves/CU TLP).
// Staging rounds (1 gld16/thread, 64 rows each): A.r0, B.r0, B.r1 (3/tile).
// Schedule per iter t (reading buf t&1):
//   [8 ds_read_b128][lgkmcnt(0)][barrier1]             <- all waves' LDS reads drained
//   [stage t+2 -> buf (now dead)][MFMA x8 setprio]
//   [vmcnt(3): t+1's 3 landed, t+2's 3 in flight][barrier2]
__global__ __launch_bounds__(512, 4) void gemm64_op(const ushort* __restrict__ A,
                                                    const ushort* __restrict__ Bt,
                                                    const float* __restrict__ bias,
                                                    float* __restrict__ C,
                                                    int M, int N, int K) {
    constexpr int BM = 64, BNT = 128;
    constexpr int A_USH = BM * 64;           // 4096
    constexpr int B_USH = BNT * 64;          // 8192
    constexpr int BUF_USH = A_USH + B_USH;   // 12288
    __shared__ ushort lds[2 * BUF_USH];      // 48 KiB

    const int tid  = threadIdx.x;
    const int wave = tid >> 6;
    const int lane = tid & 63;
    const int ln16 = lane & 15;
    const int quad = lane >> 4;
    const int wm   = wave >> 2;              // 0..1
    const int wn   = wave & 3;               // 0..3
    const int bm   = blockIdx.x * BM;
    const int bn   = blockIdx.y * BNT;

    const int r0 = tid >> 3;                 // 0..63 (row within 64-row round)
    const int c0 = ((tid & 7) - r0) & 7;     // inverse rotate swizzle
    const ushort* Abase = A  + (size_t)(bm + r0) * K + c0 * 8;
    const ushort* Bbase = Bt + (size_t)(bn + r0) * K + c0 * 8;
    const int ldst0 = wave * 512;

    const int Ra = wm * 32 + ln16;           // row mod 8 invariant across mi (mi adds 16)
    const int Rb = wn * 32 + ln16;
    int aoff[2], boff[2];
#pragma unroll
    for (int kb = 0; kb < 2; ++kb) {
        aoff[kb] = Ra * 64 + ((kb * 4 + quad + Ra) & 7) * 8;
        boff[kb] = A_USH + Rb * 64 + ((kb * 4 + quad + Rb) & 7) * 8;
    }

    ffrag acc[2][2];
#pragma unroll
    for (int mi = 0; mi < 2; ++mi)
#pragma unroll
        for (int ni = 0; ni < 2; ++ni)
            acc[mi][ni] = (ffrag){0.f, 0.f, 0.f, 0.f};

    const int nt = K >> 6;                   // 16

    auto stA = [&](int buf, int t) {
        gld16(Abase + t * 64, &lds[buf * BUF_USH + ldst0]);
    };
    auto stB = [&](int buf, int t, int rnd) {
        gld16(Bbase + (size_t)rnd * 64 * K + t * 64,
              &lds[buf * BUF_USH + A_USH + rnd * 4096 + ldst0]);
    };

    // prologue: tile0 -> buf0, tile1 -> buf1; wait tile0 (3 newest stay in flight)
    stA(0, 0); stB(0, 0, 0); stB(0, 0, 1);
    stA(1, 1); stB(1, 1, 0); stB(1, 1, 1);
    asm volatile("s_waitcnt vmcnt(3)" ::: "memory");
    __builtin_amdgcn_s_barrier();

    for (int t = 0; t < nt; ++t) {
        const int buf = t & 1;
        const ushort* Al = &lds[buf * BUF_USH];
        bfrag afr[2][2], bfr[2][2];
#pragma unroll
        for (int mi = 0; mi < 2; ++mi)
#pragma unroll
            for (int kb = 0; kb < 2; ++kb)
                afr[mi][kb] = *(const bfrag*)(Al + aoff[kb] + mi * 1024);
#pragma unroll
        for (int ni = 0; ni < 2; ++ni)
#pragma unroll
            for (int kb = 0; kb < 2; ++kb)
                bfr[ni][kb] = *(const bfrag*)(Al + boff[kb] + ni * 1024);
        asm volatile("s_waitcnt lgkmcnt(0)" ::: "memory");
        __builtin_amdgcn_sched_barrier(0);
        __builtin_amdgcn_s_barrier();        // barrier1: every wave's reads drained

        if (t + 2 < nt) {                    // stage t+2 into the now-dead current buf
            stA(buf, t + 2); stB(buf, t + 2, 0); stB(buf, t + 2, 1);
        }

        __builtin_amdgcn_s_setprio(1);
#pragma unroll
        for (int mi = 0; mi < 2; ++mi)
#pragma unroll
            for (int ni = 0; ni < 2; ++ni)
#pragma unroll
                for (int kb = 0; kb < 2; ++kb)
                    acc[mi][ni] = mfma16(afr[mi][kb], bfr[ni][kb], acc[mi][ni]);
        __builtin_amdgcn_s_setprio(0);

        if (t + 2 < nt)      { asm volatile("s_waitcnt vmcnt(3)" ::: "memory"); }
        else if (t + 1 < nt) { asm volatile("s_waitcnt vmcnt(0)" ::: "memory"); }
        __builtin_amdgcn_s_barrier();        // barrier2: next tile ready
    }

    // epilogue: fp32 row-major + bias
#pragma unroll
    for (int mi = 0; mi < 2; ++mi) {
#pragma unroll
        for (int ni = 0; ni < 2; ++ni) {
            int col = bn + wn * 32 + ni * 16 + ln16;
            float bc = bias[col];
            int row0 = bm + wm * 32 + mi * 16 + quad * 4;
#pragma unroll
            for (int reg = 0; reg < 4; ++reg)
                C[(size_t)(row0 + reg) * N + col] = acc[mi][ni][reg] + bc;
        }
    }
}

// ---------------- flash attention with near-band + closed-form far field ----------------
__global__ __launch_bounds__(512, 4) void flash_attn(const ushort* __restrict__ Qb,
                                                     const ushort* __restrict__ Kb,
                                                     const ushort* __restrict__ Vtb,
                                                     const float* __restrict__ decay_ptr,
                                                     const float* __restrict__ T,
                                                     ushort* __restrict__ Ob) {
    __shared__ ushort KVs[2][2][4096];   // [buf][K / Vt][64 rows x 8 chunks, swizzled]
    __shared__ ushort Pb[128][72];       // Q staging, then P exchange (per-wave rows)
    __shared__ float  Fv[64];            // far-field V sum per d

    const int tid  = threadIdx.x;
    const int wave = tid >> 6;
    const int lane = tid & 63;
    const int ln16 = lane & 15;
    const int quad = lane >> 4;

    const int bh = blockIdx.y;
    const int q0 = blockIdx.x * 128;
    const size_t head_off = (size_t)bh * SDIM * DDIM;
    const float absa = fabsf(decay_ptr[0]);
    const float LOG2E = 1.442695041f;
    const float M0L2 = -17.3123404f;     // -12 * log2(e)
    const float E12 = 6.144212353e-6f;   // e^-12

    int Dstar = (absa > 1e-5f) ? (int)ceilf(16.0f / absa) : (4 * SDIM);
    int lo = q0 - 63 - Dstar; if (lo < 0) lo = 0;
    int hi = q0 + 127 + Dstar; if (hi > SDIM - 1) hi = SDIM - 1;
    const int tlo = lo >> 6;
    const int thi = hi >> 6;
    const int ntiles = thi - tlo + 1;

    if (tid < 64) {
        const float* Tp = T + (size_t)bh * 32 * 64;
        float s = 0.f;
        for (int k = 0; k < tlo; ++k)      s += Tp[k * 64 + tid];
        for (int k = thi + 1; k < 32; ++k) s += Tp[k * 64 + tid];
        Fv[tid] = s;
    }

    auto stageKV = [&](int t0, int buf) {
        int g0 = wave * 64;
        int g  = g0 + lane;
        int r  = g >> 3;
        int c  = (g - r) & 7;            // inverse swizzle
        gld16(Kb  + head_off + (size_t)(t0 + r) * DDIM + c * 8,
              (ushort*)&KVs[buf][0][0] + g0 * 8);
        gld16(Vtb + head_off + (size_t)r * SDIM + t0 + c * 8,
              (ushort*)&KVs[buf][1][0] + g0 * 8);
    };

#pragma unroll
    for (int p = 0; p < 2; ++p) {
        int idx = p * 512 + tid;
        int r = idx >> 3, c = (idx & 7) * 8;
        *(uint4*)&Pb[r][c] = *(const uint4*)(Qb + head_off + (size_t)(q0 + r) * DDIM + c);
    }
    stageKV(tlo * 64, 0);
    __syncthreads();

    bfrag aq[2];
#pragma unroll
    for (int kb = 0; kb < 2; ++kb)
        aq[kb] = *(const bfrag*)&Pb[wave * 16 + ln16][kb * 32 + quad * 8];

    bfrag ones;
#pragma unroll
    for (int i = 0; i < 8; ++i) ones[i] = (short)0x3F80;   // bf16 1.0

    float EcB[4], FcB[4], Epw[4], Fpw[4];
#pragma unroll
    for (int reg = 0; reg < 4; ++reg) {
        int cr = quad * 4 + reg;
        EcB[reg] = __expf(-absa * (float)(15 - cr));
        FcB[reg] = __expf(-absa * (float)cr);
    }
#pragma unroll
    for (int ni = 0; ni < 4; ++ni) {
        Epw[ni] = __expf(-absa * (float)(16 * (3 - ni)));
        Fpw[ni] = __expf(-absa * (float)(16 * ni));
    }
    const float Er = __expf(-absa * (float)ln16);
    const float Fr = __expf(-absa * (float)(15 - ln16));

    ffrag lacc = (ffrag){0.f, 0.f, 0.f, 0.f};
    ffrag o[4];
#pragma unroll
    for (int ni = 0; ni < 4; ++ni) o[ni] = (ffrag){0.f, 0.f, 0.f, 0.f};

    const int m = wave * 16 + ln16;

    for (int it = 0; it < ntiles; ++it) {
        const int t0 = (tlo + it) * 64;
        const int buf = it & 1;
        if (it + 1 < ntiles) stageKV(t0 + 64, buf ^ 1);   // async prefetch

        const ushort* Kt = &KVs[buf][0][0];
        const ushort* Vt = &KVs[buf][1][0];

        ffrag sc[4];
#pragma unroll
        for (int ni = 0; ni < 4; ++ni) {
            ffrag a = (ffrag){0.f, 0.f, 0.f, 0.f};
            const int rk = ni * 16 + ln16;
#pragma unroll
            for (int kb = 0; kb < 2; ++kb) {
                bfrag kf = *(const bfrag*)&Kt[rk * 64 + ((kb * 4 + quad + rk) & 7) * 8];
                a = mfma16(kf, aq[kb], a);
            }
            sc[ni] = a;
        }

        const int ds = q0 + wave * 16 - t0;
        float hh = 0.f;
        if (ds >= 64)       hh = __expf(-absa * (float)(ds - 63)) * Er * LOG2E;
        else if (ds <= -16) hh = __expf(-absa * (float)(-ds - 15)) * Fr * LOG2E;

#pragma unroll
        for (int ni = 0; ni < 4; ++ni) {
            float f0, f1, f2, f3;
            if (ds >= 64) {
                float hn = hh * Epw[ni];
                f0 = hn * EcB[0]; f1 = hn * EcB[1]; f2 = hn * EcB[2]; f3 = hn * EcB[3];
            } else if (ds <= -16) {
                float hn = hh * Fpw[ni];
                f0 = hn * FcB[0]; f1 = hn * FcB[1]; f2 = hn * FcB[2]; f3 = hn * FcB[3];
            } else {
                int c0 = ni * 16 + quad * 4;
                f0 = __expf(-absa * fabsf((float)(ds + ln16 - c0)))     * LOG2E;
                f1 = __expf(-absa * fabsf((float)(ds + ln16 - c0 - 1))) * LOG2E;
                f2 = __expf(-absa * fabsf((float)(ds + ln16 - c0 - 2))) * LOG2E;
                f3 = __expf(-absa * fabsf((float)(ds + ln16 - c0 - 3))) * LOG2E;
            }
            float p0 = exp2f(fmaf(sc[ni][0], f0, M0L2));
            float p1 = exp2f(fmaf(sc[ni][1], f1, M0L2));
            float p2 = exp2f(fmaf(sc[ni][2], f2, M0L2));
            float p3 = exp2f(fmaf(sc[ni][3], f3, M0L2));
            uint2 pk;
            pk.x = pkbf2(p0, p1);
            pk.y = pkbf2(p2, p3);
            *(uint2*)&Pb[m][ni * 16 + quad * 4] = pk;   // own-wave rows: no barrier
        }

        bfrag ap[2];
#pragma unroll
        for (int kb = 0; kb < 2; ++kb)
            ap[kb] = *(const bfrag*)&Pb[m][kb * 32 + quad * 8];

#pragma unroll
        for (int kb = 0; kb < 2; ++kb)
            lacc = mfma16(ones, ap[kb], lacc);
#pragma unroll
        for (int ni = 0; ni < 4; ++ni) {
            const int rv = ni * 16 + ln16;
#pragma unroll
            for (int kb = 0; kb < 2; ++kb) {
                bfrag vf = *(const bfrag*)&Vt[rv * 64 + ((kb * 4 + quad + rv) & 7) * 8];
                o[ni] = mfma16(vf, ap[kb], o[ni]);
            }
        }
        __syncthreads();
    }

    const float farl = E12 * (float)(SDIM - 64 * ntiles);
    const float inv = 1.f / (lacc[0] + farl);
    const int b = bh / HN, h = bh % HN;
    const int s = q0 + m;
    ushort* dst = Ob + ((size_t)(b * SDIM + s)) * EDIM + h * DDIM + quad * 4;
#pragma unroll
    for (int ni = 0; ni < 4; ++ni) {
        int d0 = ni * 16 + quad * 4;
        float v0 = (o[ni][0] + E12 * Fv[d0 + 0]) * inv;
        float v1 = (o[ni][1] + E12 * Fv[d0 + 1]) * inv;
        float v2 = (o[ni][2] + E12 * Fv[d0 + 2]) * inv;
        float v3 = (o[ni][3] + E12 * Fv[d0 + 3]) * inv;
        uint2 pk;
        pk.x = pkbf2(v0, v1);
        pk.y = pkbf2(v2, v3);
        *(uint2*)(dst + ni * 16) = pk;
    }
}

extern "C" void kernel_launch(void* const* d_in, const int* in_sizes, int n_in,
                              void* d_out, int out_size, void* d_ws, size_t ws_size,
                              hipStream_t stream) {
    const float* x      = (const float*)d_in[0];
    const float* Wqkv_w = (const float*)d_in[1];
    const float* Wqkv_b = (const float*)d_in[2];
    const float* out_w  = (const float*)d_in[3];
    const float* out_b  = (const float*)d_in[4];
    const float* dd     = (const float*)d_in[5];

    char* ws = (char*)d_ws;
    const size_t MB = 1024 * 1024;
    ushort* xb    = (ushort*)(ws + 0 * MB);
    ushort* wqkvb = (ushort*)(ws + 8 * MB);
    ushort* owb   = (ushort*)(ws + 14 * MB);
    ushort* qkvb  = (ushort*)(ws + 16 * MB);   // q,k:[b,h,s,d] v:[b,h,d,s]
    ushort* ob    = (ushort*)(ws + 40 * MB);
    float*  Tp    = (float*)(ws + 48 * MB);    // own slab (gemm epilogue writes while xb live)

    const int n_x = BN * SDIM * EDIM;
    const int n_w = 3 * EDIM * EDIM;
    const int n_o = EDIM * EDIM;
    const int HSD = BN * HN * SDIM * DDIM;

    to_bf16_3<<<(n_x + n_w + n_o) / 1024, 256, 0, stream>>>(
        x, xb, n_x, Wqkv_w, wqkvb, n_w, out_w, owb, n_o);

    gemm192_qkv<0><<<dim3(32, 16), 512, 0, stream>>>(xb, wqkvb, Wqkv_b, qkvb, Tp,
                                                     BN * SDIM, 3 * EDIM, EDIM);

    flash_attn<<<dim3(SDIM / 128, BN * HN), 512, 0, stream>>>(
        qkvb, qkvb + HSD, qkvb + 2 * HSD, dd, Tp, ob);

    gemm64_op<<<dim3(64, 8), 512, 0, stream>>>(ob, owb, out_b, (float*)d_out,
                                               BN * SDIM, EDIM, EDIM);
}